// Round 11
// baseline (1091.045 us; speedup 1.0000x reference)
//
#include <hip/hip_runtime.h>
#include <hip/hip_cooperative_groups.h>
#include <math.h>

namespace cg = cooperative_groups;

#define FEATS 256
#define KTOT  512
#define MS    264   // meanS LDS row stride (elems) -- fallback fused kernel only
#define SA    40    // As/Bs LDS row stride (elems), 80B, 16B-aligned

typedef __attribute__((ext_vector_type(8))) __bf16 bf16x8;
typedef __attribute__((ext_vector_type(4))) float f32x4;

// async global->LDS 16B: dest = wave-uniform base + lane*16 (lane-linear)
#define ASYNC16(G, L) __builtin_amdgcn_global_load_lds( \
    (const __attribute__((address_space(1))) unsigned int*)(G), \
    (__attribute__((address_space(3))) unsigned int*)(L), 16, 0, 0)

__device__ __forceinline__ float bf2f(unsigned short u) {
    union { unsigned int i; float f; } v; v.i = ((unsigned int)u) << 16; return v.f;
}
__device__ __forceinline__ unsigned short f2bf(float f) {
    unsigned int u = __float_as_uint(f);
    unsigned int r = (u + 0x7FFFu + ((u >> 16) & 1u)) >> 16;
    return (unsigned short)r;
}
// read weight elem as bf16 from either dtype
__device__ __forceinline__ unsigned short rdw(const void* W, size_t i, bool f32m) {
    return f32m ? f2bf(((const float*)W)[i]) : ((const unsigned short*)W)[i];
}

// =====================================================================
// Cooperative prep: replaces detect + memset + count + bsum + scanb +
// offs + fill + buildAll (8 dispatches -> 1). Phases separated by
// grid.sync(); 1024 blocks co-resident (4/CU, tiny kernel).
// =====================================================================
__global__ __launch_bounds__(256) void k_prep(
        const int* srcRaw, const int* dstRaw, const unsigned short* xr,
        int nE, int nNodes, int nodeBlocks, int C,
        int* flag, int* deg, int* bsum, int* off, int* cursor, int* csr,
        const void* Ws0, const void* Wn0, const void* Ws1, const void* Wn1,
        const void* Ws2, const void* Wn2,
        unsigned short* Wt0, unsigned short* Wt1,
        unsigned short* Wt2s, unsigned short* Wt2n) {
    cg::grid_group grid = cg::this_grid();
    const int tid = threadIdx.x;
    const int gid = blockIdx.x * 256 + tid;
    const int gsz = gridDim.x * 256;
    __shared__ int buf[256];
    __shared__ int sAny, sCnt, carry;

    // ---- phase 0: zero deg; block 0 detects dtypes ----
    for (int i = gid; i < nNodes; i += gsz) deg[i] = 0;
    if (blockIdx.x == 0) {
        if (tid == 0) { sAny = 0; sCnt = 0; }
        __syncthreads();
        int lim = nE < 1024 ? nE : 1024;
        for (int i = tid; i < lim; i += 256)
            if (srcRaw[2 * i + 1] != 0) atomicAdd(&sAny, 1);
        int loc = 0;
        for (int i = tid; i < 1024; i += 256) {
            unsigned e = (xr[2 * i] >> 7) & 255u;
            if (e >= 90u && e <= 140u) loc++;
        }
        atomicAdd(&sCnt, loc);
        __syncthreads();
        if (tid == 0) { flag[0] = (sAny == 0) ? 1 : 0; flag[1] = (sCnt > 512) ? 1 : 0; }
    }
    grid.sync();

    // ---- phase 1: degree count + all weight transposes ----
    const int f = flag[0];
    const bool f32m = (flag[1] == 0);
    for (int e = gid; e < nE; e += gsz) {
        int d = dstRaw[f ? (2 * e) : e];
        if ((unsigned)d >= (unsigned)nNodes) d = 0;
        atomicAdd(&deg[d], 1);
    }
    for (int idx = gid; idx < 294912; idx += gsz) {
        if (idx < 262144) {                       // Wt0 / Wt1: n<256, k<512
            const bool one = idx >= 131072;
            int j = one ? idx - 131072 : idx;
            int n = j >> 9, k = j & 511;
            const void* Ws = one ? Ws1 : Ws0;
            const void* Wn = one ? Wn1 : Wn0;
            unsigned short v = (k < 256) ? rdw(Ws, (size_t)k * 256 + n, f32m)
                                         : rdw(Wn, (size_t)(k - 256) * 256 + n, f32m);
            (one ? Wt1 : Wt0)[j] = v;
        } else {                                  // Wt2s / Wt2n: n<64 pad, k<256
            const bool nw = idx >= 278528;
            int j = nw ? idx - 278528 : idx - 262144;
            int n = j >> 8, k = j & 255;
            unsigned short v = 0;
            if (n < C) v = rdw(nw ? Wn2 : Ws2, (size_t)k * C + n, f32m);
            (nw ? Wt2n : Wt2s)[j] = v;
        }
    }
    grid.sync();

    // ---- phase 2: per-chunk sums (nodeBlocks <= gridDim) ----
    if (blockIdx.x < nodeBlocks) {
        int i = blockIdx.x * 256 + tid;
        buf[tid] = (i < nNodes) ? deg[i] : 0;
        __syncthreads();
        for (int s = 128; s > 0; s >>= 1) {
            if (tid < s) buf[tid] += buf[tid + s];
            __syncthreads();
        }
        if (tid == 0) bsum[blockIdx.x] = buf[0];
    }
    grid.sync();

    // ---- phase 3: block 0 exclusive-scans bsum ----
    if (blockIdx.x == 0) {
        if (tid == 0) carry = 0;
        __syncthreads();
        for (int base = 0; base < nodeBlocks; base += 256) {
            int i = base + tid;
            int v = (i < nodeBlocks) ? bsum[i] : 0;
            buf[tid] = v;
            __syncthreads();
            for (int s = 1; s < 256; s <<= 1) {
                int tv = (tid >= s) ? buf[tid - s] : 0;
                __syncthreads();
                buf[tid] += tv;
                __syncthreads();
            }
            int exc = buf[tid] - v;
            int c = carry;
            if (i < nodeBlocks) bsum[i] = c + exc;
            int tot = buf[255];
            __syncthreads();
            if (tid == 0) carry = c + tot;
            __syncthreads();
        }
    }
    grid.sync();

    // ---- phase 4: local scan + block prefix -> off, cursor ----
    if (blockIdx.x < nodeBlocks) {
        int i = blockIdx.x * 256 + tid;
        int v = (i < nNodes) ? deg[i] : 0;
        buf[tid] = v;
        __syncthreads();
        for (int s = 1; s < 256; s <<= 1) {
            int tv = (tid >= s) ? buf[tid - s] : 0;
            __syncthreads();
            buf[tid] += tv;
            __syncthreads();
        }
        int exc = bsum[blockIdx.x] + buf[tid] - v;
        if (i < nNodes) { off[i] = exc; cursor[i] = exc; }
        if (i == nNodes - 1) off[nNodes] = exc + v;
    }
    grid.sync();

    // ---- phase 5: fill csr ----
    for (int e = gid; e < nE; e += gsz) {
        int d = dstRaw[f ? (2 * e) : e];
        int s = srcRaw[f ? (2 * e) : e];
        if ((unsigned)d >= (unsigned)nNodes) d = 0;
        if ((unsigned)s >= (unsigned)nNodes) s = 0;
        int pos = atomicAdd(&cursor[d], 1);
        csr[pos] = s;
    }
}

// ---------------------------------------------------------------------
// Fallback (non-coop) prep kernels — verified from earlier rounds.
// ---------------------------------------------------------------------
__global__ void k_detect(const int* __restrict__ srcRaw, const unsigned short* __restrict__ xr,
                         int nE, int* __restrict__ flag) {
    __shared__ int any, cnt;
    if (threadIdx.x == 0) { any = 0; cnt = 0; }
    __syncthreads();
    int lim = nE < 1024 ? nE : 1024;
    for (int i = threadIdx.x; i < lim; i += 256)
        if (srcRaw[2 * i + 1] != 0) atomicAdd(&any, 1);
    int loc = 0;
    for (int i = threadIdx.x; i < 1024; i += 256) {
        unsigned e = (xr[2 * i] >> 7) & 255u;
        if (e >= 90u && e <= 140u) loc++;
    }
    atomicAdd(&cnt, loc);
    __syncthreads();
    if (threadIdx.x == 0) {
        flag[0] = (any == 0) ? 1 : 0;
        flag[1] = (cnt > 512) ? 1 : 0;
    }
}

__global__ void k_count(const int* __restrict__ dstRaw, int* __restrict__ deg, int nE,
                        int nNodes, const int* __restrict__ flag) {
    int e = blockIdx.x * 256 + threadIdx.x;
    if (e >= nE) return;
    int f = flag[0];
    int d = dstRaw[f ? (2 * e) : e];
    if ((unsigned)d >= (unsigned)nNodes) d = 0;
    atomicAdd(&deg[d], 1);
}

__global__ __launch_bounds__(256) void k_bsum(const int* __restrict__ deg, int* __restrict__ bsum,
                                              int n) {
    __shared__ int buf[256];
    const int t = threadIdx.x;
    int i = blockIdx.x * 256 + t;
    buf[t] = (i < n) ? deg[i] : 0;
    __syncthreads();
    for (int s = 128; s > 0; s >>= 1) {
        if (t < s) buf[t] += buf[t + s];
        __syncthreads();
    }
    if (t == 0) bsum[blockIdx.x] = buf[0];
}

__global__ __launch_bounds__(256) void k_scanb(int* __restrict__ bsum, int nB) {
    __shared__ int buf[256];
    __shared__ int carry;
    const int t = threadIdx.x;
    if (t == 0) carry = 0;
    __syncthreads();
    for (int base = 0; base < nB; base += 256) {
        int i = base + t;
        int v = (i < nB) ? bsum[i] : 0;
        buf[t] = v;
        __syncthreads();
        for (int s = 1; s < 256; s <<= 1) {
            int tv = (t >= s) ? buf[t - s] : 0;
            __syncthreads();
            buf[t] += tv;
            __syncthreads();
        }
        int exc = buf[t] - v;
        int c = carry;
        if (i < nB) bsum[i] = c + exc;
        int tot = buf[255];
        __syncthreads();
        if (t == 0) carry = c + tot;
        __syncthreads();
    }
}

__global__ __launch_bounds__(256) void k_offs(const int* __restrict__ deg,
                                              const int* __restrict__ bsum,
                                              int* __restrict__ off, int* __restrict__ cursor,
                                              int n) {
    __shared__ int buf[256];
    const int t = threadIdx.x, b = blockIdx.x;
    int i = b * 256 + t;
    int v = (i < n) ? deg[i] : 0;
    buf[t] = v;
    __syncthreads();
    for (int s = 1; s < 256; s <<= 1) {
        int tv = (t >= s) ? buf[t - s] : 0;
        __syncthreads();
        buf[t] += tv;
        __syncthreads();
    }
    int exc = bsum[b] + buf[t] - v;
    if (i < n) { off[i] = exc; cursor[i] = exc; }
    if (i == n - 1) off[n] = exc + v;
}

__global__ void k_fill(const int* __restrict__ srcRaw, const int* __restrict__ dstRaw,
                       int* __restrict__ cursor, int* __restrict__ csr, int nE,
                       int nNodes, const int* __restrict__ flag) {
    int e = blockIdx.x * 256 + threadIdx.x;
    if (e >= nE) return;
    int f = flag[0];
    int d = dstRaw[f ? (2 * e) : e];
    int s = srcRaw[f ? (2 * e) : e];
    if ((unsigned)d >= (unsigned)nNodes) d = 0;
    if ((unsigned)s >= (unsigned)nNodes) s = 0;
    int pos = atomicAdd(&cursor[d], 1);
    csr[pos] = s;
}

__global__ __launch_bounds__(256) void k_buildAll(
        const void* __restrict__ Ws0, const void* __restrict__ Wn0,
        const void* __restrict__ Ws1, const void* __restrict__ Wn1,
        const void* __restrict__ Ws2, const void* __restrict__ Wn2,
        unsigned short* __restrict__ Wt0, unsigned short* __restrict__ Wt1,
        unsigned short* __restrict__ Wt2s, unsigned short* __restrict__ Wt2n,
        int C, const int* __restrict__ flag) {
    const bool f32m = (flag[1] == 0);
    int idx = blockIdx.x * 256 + threadIdx.x;
    if (idx < 262144) {
        const bool one = idx >= 131072;
        int j = one ? idx - 131072 : idx;
        int n = j >> 9, k = j & 511;
        const void* Ws = one ? Ws1 : Ws0;
        const void* Wn = one ? Wn1 : Wn0;
        unsigned short v = (k < 256) ? rdw(Ws, (size_t)k * 256 + n, f32m)
                                     : rdw(Wn, (size_t)(k - 256) * 256 + n, f32m);
        (one ? Wt1 : Wt0)[j] = v;
    } else if (idx < 294912) {
        const bool nw = idx >= 278528;
        int j = nw ? idx - 278528 : idx - 262144;
        int n = j >> 8, k = j & 255;
        unsigned short v = 0;
        if (n < C) v = rdw(nw ? Wn2 : Ws2, (size_t)k * C + n, f32m);
        (nw ? Wt2n : Wt2s)[j] = v;
    }
}

// =====================================================================
// Proven aggregator (121 us @ 3.37 TB/s roofline for random 512B
// gathers): wave per row, zero LDS. Runtime dtype branch.
// =====================================================================
__global__ __launch_bounds__(256) void k_aggr(
        const void* __restrict__ h, const int* __restrict__ off,
        const int* __restrict__ csr, unsigned short* __restrict__ hmean,
        int M, const int* __restrict__ flag, int maybeF32) {
    const bool f32m = maybeF32 && (flag[1] == 0);
    const int lane = threadIdx.x & 63;
    const int wid = (blockIdx.x * 256 + threadIdx.x) >> 6;
    const int nw = (gridDim.x * 256) >> 6;
    if (f32m) {
        for (int r = wid; r < M; r += nw) {
            const int e0 = off[r], e1 = off[r + 1];
            float a0 = 0.f, a1 = 0.f, a2 = 0.f, a3 = 0.f;
            for (int base = e0; base < e1; base += 64) {
                int cnt = e1 - base; if (cnt > 64) cnt = 64;
                int sidx = (lane < cnt) ? csr[base + lane] : 0;
                #pragma unroll 8
                for (int d = 0; d < cnt; d++) {
                    int s = __shfl(sidx, d);
                    float4 hv = reinterpret_cast<const float4*>(
                        (const float*)h + (size_t)s * FEATS)[lane];
                    a0 += hv.x; a1 += hv.y; a2 += hv.z; a3 += hv.w;
                }
            }
            float rc = 1.0f / fmaxf((float)(e1 - e0), 1.0f);
            ushort4 o;
            o.x = f2bf(a0 * rc); o.y = f2bf(a1 * rc); o.z = f2bf(a2 * rc); o.w = f2bf(a3 * rc);
            *reinterpret_cast<ushort4*>(&hmean[(size_t)r * FEATS + lane * 4]) = o;
        }
    } else {
        for (int r = wid; r < M; r += nw) {
            const int e0 = off[r], e1 = off[r + 1];
            float a0 = 0.f, a1 = 0.f, a2 = 0.f, a3 = 0.f;
            for (int base = e0; base < e1; base += 64) {
                int cnt = e1 - base; if (cnt > 64) cnt = 64;
                int sidx = (lane < cnt) ? csr[base + lane] : 0;
                #pragma unroll 8
                for (int d = 0; d < cnt; d++) {
                    int s = __shfl(sidx, d);
                    ushort4 hv = reinterpret_cast<const ushort4*>(
                        (const unsigned short*)h + (size_t)s * FEATS)[lane];
                    a0 += bf2f(hv.x); a1 += bf2f(hv.y); a2 += bf2f(hv.z); a3 += bf2f(hv.w);
                }
            }
            float rc = 1.0f / fmaxf((float)(e1 - e0), 1.0f);
            ushort4 o;
            o.x = f2bf(a0 * rc); o.y = f2bf(a1 * rc); o.z = f2bf(a2 * rc); o.w = f2bf(a3 * rc);
            *reinterpret_cast<ushort4*>(&hmean[(size_t)r * FEATS + lane * 4]) = o;
        }
    }
}

// =====================================================================
// Lean GEMM (layers 0/1): 64 rows x 128 cols per block, BK=64,
// global_load_lds width-16 into linear LDS with chunk^(row&7) swizzle.
// =====================================================================
__global__ __launch_bounds__(256) void k_gemm(
        const void* __restrict__ h, const unsigned short* __restrict__ hmean,
        const unsigned short* __restrict__ Wt, const void* __restrict__ bias,
        void* __restrict__ out, int M, const int* __restrict__ flag, int maybeF32) {
    const bool inF32 = (flag[1] == 0);
    const bool hF32 = maybeF32 && inF32;
    __shared__ __align__(16) unsigned short As[64 * 64];    // 8 KB
    __shared__ __align__(16) unsigned short Bs[128 * 64];   // 16 KB

    const int rb = (int)blockIdx.x >> 1;
    const int chalf = (int)blockIdx.x & 1;
    const int m0 = rb * 64;
    const int col0 = chalf * 128;
    const int tid = threadIdx.x;
    const int lane = tid & 63, w = tid >> 6;
    const int nh = lane & 15, q = lane >> 4;   // q in 0..3

    f32x4 acc[8];
    #pragma unroll
    for (int ci = 0; ci < 8; ci++) acc[ci] = (f32x4){0.f, 0.f, 0.f, 0.f};

    for (int kb = 0; kb < KTOT; kb += 64) {
        #pragma unroll
        for (int j = 0; j < 2; j++) {
            int t2 = tid + j * 256;
            int row = t2 >> 3, c = t2 & 7;
            int gr = m0 + row; if (gr > M - 1) gr = M - 1;
            int cs = c ^ (row & 7);
            if (kb < 256) {
                if (hF32) {
                    const float* p = (const float*)h + (size_t)gr * FEATS + kb + cs * 8;
                    float4 a = *reinterpret_cast<const float4*>(p);
                    float4 b = *reinterpret_cast<const float4*>(p + 4);
                    unsigned short* d = &As[t2 * 8];
                    d[0]=f2bf(a.x); d[1]=f2bf(a.y); d[2]=f2bf(a.z); d[3]=f2bf(a.w);
                    d[4]=f2bf(b.x); d[5]=f2bf(b.y); d[6]=f2bf(b.z); d[7]=f2bf(b.w);
                } else {
                    ASYNC16((const unsigned short*)h + (size_t)gr * FEATS + kb + cs * 8,
                            &As[t2 * 8]);
                }
            } else {
                ASYNC16(hmean + (size_t)gr * FEATS + (kb - 256) + cs * 8, &As[t2 * 8]);
            }
        }
        #pragma unroll
        for (int j = 0; j < 4; j++) {
            int t2 = tid + j * 256;
            int n = t2 >> 3, c = t2 & 7;
            int cs = c ^ (n & 7);
            ASYNC16(Wt + (size_t)(col0 + n) * KTOT + kb + cs * 8, &Bs[t2 * 8]);
        }
        __syncthreads();

        #pragma unroll
        for (int s = 0; s < 2; s++) {
            const int arow = w * 16 + nh;
            const int qa = ((s * 4 + q) ^ (arow & 7));
            bf16x8 afr = *reinterpret_cast<const bf16x8*>(&As[arow * 64 + qa * 8]);
            #pragma unroll
            for (int ci = 0; ci < 8; ci++) {
                int n = ci * 16 + nh;
                int qb = ((s * 4 + q) ^ (n & 7));
                bf16x8 bfr = *reinterpret_cast<const bf16x8*>(&Bs[n * 64 + qb * 8]);
                acc[ci] = __builtin_amdgcn_mfma_f32_16x16x32_bf16(afr, bfr, acc[ci], 0, 0, 0);
            }
        }
        __syncthreads();
    }

    const int rbase = m0 + w * 16 + q * 4;
    const float sc = 1.0507009873554805f, al = 1.6732632423543772f;
    #pragma unroll
    for (int ci = 0; ci < 8; ci++) {
        int col = col0 + ci * 16 + nh;
        float b = inF32 ? ((const float*)bias)[col] : bf2f(((const unsigned short*)bias)[col]);
        #pragma unroll
        for (int rg = 0; rg < 4; rg++) {
            int r = rbase + rg;
            if (r < M) {
                float v = acc[ci][rg] + b;
                v = (v > 0.f) ? sc * v : sc * al * expm1f(v);
                ((unsigned short*)out)[(size_t)r * FEATS + col] = f2bf(v);
            }
        }
    }
}

// =====================================================================
// Layer-2 dual GEMM (single hX pass): S2 = hX @ Ws2 (f32, stride 64)
// AND P2 = hX @ Wn2 (bf16, stride 64). 64 rows x 128 cols, K=256.
// =====================================================================
__global__ __launch_bounds__(256) void k_gemm256d(
        const unsigned short* __restrict__ h, const unsigned short* __restrict__ Wt2s,
        const unsigned short* __restrict__ Wt2n, float* __restrict__ S2,
        unsigned short* __restrict__ P2, int M) {
    __shared__ __align__(16) unsigned short As[64 * SA];
    __shared__ __align__(16) unsigned short Bs[128 * SA];

    const int m0 = blockIdx.x * 64;
    const int tid = threadIdx.x;
    const int lane = tid & 63, w = tid >> 6;
    const int nh = lane & 15, q = lane >> 4;

    f32x4 acc[8];
    #pragma unroll
    for (int ci = 0; ci < 8; ci++) acc[ci] = (f32x4){0.f, 0.f, 0.f, 0.f};

    for (int kb = 0; kb < 256; kb += 32) {
        {
            int row = tid >> 2, seg = tid & 3;
            int gr = m0 + row; if (gr > M - 1) gr = M - 1;
            *reinterpret_cast<float4*>(&As[row * SA + seg * 8]) =
                *reinterpret_cast<const float4*>(h + (size_t)gr * FEATS + kb + seg * 8);
        }
        for (int u = tid; u < 128 * 4; u += 256) {
            int nn = u >> 2, seg = u & 3;
            const unsigned short* src = (nn < 64)
                ? Wt2s + (size_t)nn * 256 : Wt2n + (size_t)(nn - 64) * 256;
            *reinterpret_cast<float4*>(&Bs[nn * SA + seg * 8]) =
                *reinterpret_cast<const float4*>(src + kb + seg * 8);
        }
        __syncthreads();
        bf16x8 afr = *reinterpret_cast<const bf16x8*>(&As[(w * 16 + nh) * SA + q * 8]);
        #pragma unroll
        for (int ci = 0; ci < 8; ci++) {
            bf16x8 bfr = *reinterpret_cast<const bf16x8*>(&Bs[(ci * 16 + nh) * SA + q * 8]);
            acc[ci] = __builtin_amdgcn_mfma_f32_16x16x32_bf16(afr, bfr, acc[ci], 0, 0, 0);
        }
        __syncthreads();
    }

    const int rbase = m0 + w * 16 + q * 4;
    #pragma unroll
    for (int ci = 0; ci < 4; ci++) {       // self half -> S2 (f32)
        int col = ci * 16 + nh;
        #pragma unroll
        for (int rg = 0; rg < 4; rg++) {
            int r = rbase + rg;
            if (r < M) S2[(size_t)r * 64 + col] = acc[ci][rg];
        }
    }
    #pragma unroll
    for (int ci = 4; ci < 8; ci++) {       // neigh half -> P2 (bf16)
        int col = (ci - 4) * 16 + nh;
        #pragma unroll
        for (int rg = 0; rg < 4; rg++) {
            int r = rbase + rg;
            if (r < M) P2[(size_t)r * 64 + col] = f2bf(acc[ci][rg]);
        }
    }
}

// =====================================================================
// FUSED layer-2 tail: gather-mean of P2 (wave per row, 2 grp x 32 ln)
// + softmax(S2 + mean + b2) in-register. Replaces aggrP + smax.
// FIX (r10): redistribution shuffles are now executed by ALL lanes
// (full exec mask) then selected — divergent ds_bpermute reads from
// inactive source lanes return 0 on CDNA, which corrupted ~half the
// columns in round 10.
// =====================================================================
__global__ __launch_bounds__(256) void k_aggrsm(
        const unsigned short* __restrict__ P, const float* __restrict__ S2,
        const int* __restrict__ off, const int* __restrict__ csr,
        const void* __restrict__ bias, void* __restrict__ out,
        int M, int C, const int* __restrict__ flag) {
    const bool inF32 = (flag[1] == 0);
    const int lane = threadIdx.x & 63;
    const int wid = (blockIdx.x * 256 + threadIdx.x) >> 6;
    const int nw = (gridDim.x * 256) >> 6;
    const int g = lane >> 5, li = lane & 31;
    for (int r = wid; r < M; r += nw) {
        const int e0 = off[r], e1 = off[r + 1];
        float a0 = 0.f, a1 = 0.f;
        #pragma unroll 4
        for (int base = e0; base < e1; base += 2) {
            int e = base + g;
            if (e < e1) {
                int s = csr[e];
                ushort2 hv = *reinterpret_cast<const ushort2*>(
                    P + (size_t)s * 64 + li * 2);
                a0 += bf2f(hv.x); a1 += bf2f(hv.y);
            }
        }
        a0 += __shfl_xor(a0, 32); a1 += __shfl_xor(a1, 32);   // all lanes hold totals
        float rc = 1.0f / fmaxf((float)(e1 - e0), 1.0f);
        // redistribute: col c lives in (c&1 ? a1 : a0) of lane c>>1.
        // Execute BOTH shuffles with full exec mask, then select.
        float av0 = __shfl(a0, lane >> 1);
        float av1 = __shfl(a1, lane >> 1);
        float av = (lane & 1) ? av1 : av0;
        float v = -1e30f;
        if (lane < C) {
            float b = inF32 ? ((const float*)bias)[lane]
                            : bf2f(((const unsigned short*)bias)[lane]);
            v = S2[(size_t)r * 64 + lane] + av * rc + b;
        }
        float mx = v;
        #pragma unroll
        for (int mk = 1; mk <= 32; mk <<= 1) mx = fmaxf(mx, __shfl_xor(mx, mk));
        float e = (lane < C) ? __expf(v - mx) : 0.f;
        float s = e;
        #pragma unroll
        for (int mk = 1; mk <= 32; mk <<= 1) s += __shfl_xor(s, mk);
        float o = e / s;
        if (lane < C) {
            if (inF32) ((float*)out)[(size_t)r * C + lane] = o;
            else ((unsigned short*)out)[(size_t)r * C + lane] = f2bf(o);
        }
    }
}

// =====================================================================
// FALLBACK path kernels (workspace too small): original fused kernel +
// dual-dtype weight transpose. Verified-correct from earlier sessions.
// =====================================================================
template <bool F32>
__global__ void k_buildWt(const void* __restrict__ Ws, const void* __restrict__ Wn,
                          unsigned short* __restrict__ Wt, int N, int Npad,
                          const int* __restrict__ flag) {
    if (flag[1] != (F32 ? 0 : 1)) return;
    int idx = blockIdx.x * 256 + threadIdx.x;
    if (idx >= Npad * KTOT) return;
    int n = idx >> 9, k = idx & 511;
    unsigned short v = 0;
    if (n < N) {
        if (F32) {
            float fv = (k < 256) ? ((const float*)Ws)[k * N + n]
                                 : ((const float*)Wn)[(k - 256) * N + n];
            v = f2bf(fv);
        } else {
            v = (k < 256) ? ((const unsigned short*)Ws)[k * N + n]
                          : ((const unsigned short*)Wn)[(k - 256) * N + n];
        }
    }
    Wt[idx] = v;
}

template <bool F32>
__device__ __forceinline__ void stage8(const void* h, size_t elemOff, unsigned short* dst) {
    if (!F32) {
        *reinterpret_cast<float4*>(dst) =
            *reinterpret_cast<const float4*>((const unsigned short*)h + elemOff);
    } else {
        const float* p = (const float*)h + elemOff;
        float4 a = *reinterpret_cast<const float4*>(p);
        float4 b = *reinterpret_cast<const float4*>(p + 4);
        dst[0] = f2bf(a.x); dst[1] = f2bf(a.y); dst[2] = f2bf(a.z); dst[3] = f2bf(a.w);
        dst[4] = f2bf(b.x); dst[5] = f2bf(b.y); dst[6] = f2bf(b.z); dst[7] = f2bf(b.w);
    }
}

template <int NT, int ACT, bool HF32, bool BF32, bool OF32>
__global__ __launch_bounds__(256) void k_sage(
        const void* __restrict__ h, const int* __restrict__ off,
        const int* __restrict__ csr, const unsigned short* __restrict__ Wt,
        const void* __restrict__ bias, void* __restrict__ out,
        int M, int C, const int* __restrict__ flag, int want) {
    if (flag[1] != want) return;
    __shared__ __align__(16) unsigned short meanS[64 * MS];
    __shared__ __align__(16) unsigned short As[64 * SA];
    __shared__ __align__(16) unsigned short Bs[NT * 16 * SA];

    const int m0 = blockIdx.x * 64;
    const int tid = threadIdx.x;
    const int lane = tid & 63, w = tid >> 6;
    const int nh = lane & 15, q = lane >> 4;

    for (int i = 0; i < 16; i++) {
        int lr = w * 16 + i;
        int r = m0 + lr;
        int rr = (r < M) ? r : (M - 1);
        int e0 = off[rr], e1 = off[rr + 1];
        float a0 = 0.f, a1 = 0.f, a2 = 0.f, a3 = 0.f;
        #pragma unroll 8
        for (int j = e0; j < e1; j++) {
            int s = csr[j];
            if (HF32) {
                float4 hv = reinterpret_cast<const float4*>((const float*)h + (size_t)s * FEATS)[lane];
                a0 += hv.x; a1 += hv.y; a2 += hv.z; a3 += hv.w;
            } else {
                ushort4 hv = reinterpret_cast<const ushort4*>((const unsigned short*)h + (size_t)s * FEATS)[lane];
                a0 += bf2f(hv.x); a1 += bf2f(hv.y); a2 += bf2f(hv.z); a3 += bf2f(hv.w);
            }
        }
        float rc = 1.0f / fmaxf((float)(e1 - e0), 1.0f);
        ushort4 o;
        o.x = f2bf(a0 * rc); o.y = f2bf(a1 * rc); o.z = f2bf(a2 * rc); o.w = f2bf(a3 * rc);
        *reinterpret_cast<ushort4*>(&meanS[lr * MS + lane * 4]) = o;
    }
    __syncthreads();

    f32x4 acc[NT];
    #pragma unroll
    for (int ci = 0; ci < NT; ci++) acc[ci] = (f32x4){0.f, 0.f, 0.f, 0.f};

    for (int kb = 0; kb < KTOT; kb += 32) {
        const bool fromMean = (kb >= 256);
        if (!fromMean) {
            int row = tid >> 2, seg = tid & 3;
            int gr = m0 + row; if (gr > M - 1) gr = M - 1;
            stage8<HF32>(h, (size_t)gr * FEATS + kb + seg * 8, &As[row * SA + seg * 8]);
        }
        for (int u = tid; u < NT * 64; u += 256) {
            int nn = u >> 2, seg = u & 3;
            *reinterpret_cast<float4*>(&Bs[nn * SA + seg * 8]) =
                *reinterpret_cast<const float4*>(Wt + (size_t)nn * KTOT + kb + seg * 8);
        }
        __syncthreads();
        bf16x8 afr;
        if (!fromMean)
            afr = *reinterpret_cast<const bf16x8*>(&As[(w * 16 + nh) * SA + q * 8]);
        else
            afr = *reinterpret_cast<const bf16x8*>(&meanS[(w * 16 + nh) * MS + (kb - 256) + q * 8]);
        #pragma unroll
        for (int ci = 0; ci < NT; ci++) {
            bf16x8 bfr = *reinterpret_cast<const bf16x8*>(&Bs[(ci * 16 + nh) * SA + q * 8]);
            acc[ci] = __builtin_amdgcn_mfma_f32_16x16x32_bf16(afr, bfr, acc[ci], 0, 0, 0);
        }
        __syncthreads();
    }

    const int rbase = m0 + w * 16 + q * 4;
    if (ACT == 0) {
        const float sc = 1.0507009873554805f, al = 1.6732632423543772f;
        #pragma unroll
        for (int ci = 0; ci < NT; ci++) {
            int col = ci * 16 + nh;
            float b = BF32 ? ((const float*)bias)[col] : bf2f(((const unsigned short*)bias)[col]);
            #pragma unroll
            for (int rg = 0; rg < 4; rg++) {
                int r = rbase + rg;
                if (r < M) {
                    float v = acc[ci][rg] + b;
                    v = (v > 0.f) ? sc * v : sc * al * expm1f(v);
                    if (OF32) ((float*)out)[(size_t)r * (NT * 16) + col] = v;
                    else ((unsigned short*)out)[(size_t)r * (NT * 16) + col] = f2bf(v);
                }
            }
        }
    } else {
        #pragma unroll
        for (int rg = 0; rg < 4; rg++) {
            int r = rbase + rg;
            float vals[NT];
            float mx = -1e30f;
            #pragma unroll
            for (int ci = 0; ci < NT; ci++) {
                int col = ci * 16 + nh;
                float v = -1e30f;
                if (col < C) {
                    float b = BF32 ? ((const float*)bias)[col] : bf2f(((const unsigned short*)bias)[col]);
                    v = acc[ci][rg] + b;
                }
                vals[ci] = v;
                mx = fmaxf(mx, v);
            }
            #pragma unroll
            for (int mk = 1; mk <= 8; mk <<= 1) mx = fmaxf(mx, __shfl_xor(mx, mk));
            float s = 0.f;
            #pragma unroll
            for (int ci = 0; ci < NT; ci++) {
                float e = (vals[ci] <= -1e29f) ? 0.f : __expf(vals[ci] - mx);
                vals[ci] = e; s += e;
            }
            #pragma unroll
            for (int mk = 1; mk <= 8; mk <<= 1) s += __shfl_xor(s, mk);
            float inv = 1.f / s;
            if (r < M) {
                #pragma unroll
                for (int ci = 0; ci < NT; ci++) {
                    int col = ci * 16 + nh;
                    if (col < C) {
                        if (OF32) ((float*)out)[(size_t)r * C + col] = vals[ci] * inv;
                        else ((unsigned short*)out)[(size_t)r * C + col] = f2bf(vals[ci] * inv);
                    }
                }
            }
        }
    }
}

extern "C" void kernel_launch(void* const* d_in, const int* in_sizes, int n_in,
                              void* d_out, int out_size, void* d_ws, size_t ws_size,
                              hipStream_t stream) {
    const int* srcRaw = (const int*)d_in[1];
    const int* dstRaw = (const int*)d_in[2];
    const void* x   = d_in[0];
    const void* Ws0 = d_in[3]; const void* Wn0 = d_in[4]; const void* b0 = d_in[5];
    const void* Ws1 = d_in[6]; const void* Wn1 = d_in[7]; const void* b1 = d_in[8];
    const void* Ws2 = d_in[9]; const void* Wn2 = d_in[10]; const void* b2 = d_in[11];

    const int nNodes = in_sizes[0] / FEATS;   // 50000
    const int nE     = in_sizes[1];           // 800000
    const int C      = in_sizes[11];          // 47

    // ---- workspace carve ----
    char* ws = (char*)d_ws;
    size_t off_b = 0;
    auto carve = [&](size_t bytes) -> void* {
        void* p = (void*)(ws + off_b);
        off_b += (bytes + 255) & ~(size_t)255;
        return p;
    };
    int*            flag   = (int*)           carve(256);
    int*            deg    = (int*)           carve((size_t)nNodes * 4);
    int*            cursor = (int*)           carve((size_t)nNodes * 4);
    int*            off    = (int*)           carve((size_t)(nNodes + 1) * 4);
    int*            csr    = (int*)           carve((size_t)nE * 4);
    unsigned short* Wt0    = (unsigned short*)carve((size_t)256 * KTOT * 2);
    unsigned short* Wt1    = (unsigned short*)carve((size_t)256 * KTOT * 2);
    unsigned short* Wt2    = (unsigned short*)carve((size_t)64 * KTOT * 2);   // fallback combined
    unsigned short* Wt2s   = (unsigned short*)carve((size_t)64 * 256 * 2);
    unsigned short* Wt2n   = (unsigned short*)carve((size_t)64 * 256 * 2);
    int*            bsum   = (int*)           carve(4096);
    unsigned short* hA     = (unsigned short*)carve((size_t)nNodes * FEATS * 2);
    unsigned short* hmean  = (unsigned short*)carve((size_t)nNodes * FEATS * 2);
    const bool split = (off_b <= ws_size);
    // layer-2 buffers tile into hmean (dead for layer 2):
    //   S2 f32 (nN*64*4 B) | P2 bf16 (nN*64*2 B)
    const size_t l2n = (size_t)nNodes * 64;
    float*          S2 = (float*)hmean;                 // bytes [0, 4*l2n)
    unsigned short* P2 = hmean + l2n * 2;               // bytes [4*l2n, 6*l2n)
    // h2 lives in the (dead-after-layer-0, harness-restored) x input buffer
    unsigned short* hX = (unsigned short*)d_in[0];

    const int edgeBlocks = (nE + 255) / 256;
    const int nodeBlocks = (nNodes + 255) / 256;   // 196 <= 1024
    const int sageBlocks = (nNodes + 63) / 64;     // 782
    const int gemmBlocks = sageBlocks * 2;         // 64x128 tiles, col-half split
    const int aggrBlocks = 2048;

    if (split) {
        // ---- cooperative prep: detect + CSR build + weight transposes ----
        const unsigned short* xr = (const unsigned short*)x;
        int nE_v = nE, nN_v = nNodes, nB_v = nodeBlocks, C_v = C;
        void* cargs[] = {
            (void*)&srcRaw, (void*)&dstRaw, (void*)&xr,
            (void*)&nE_v, (void*)&nN_v, (void*)&nB_v, (void*)&C_v,
            (void*)&flag, (void*)&deg, (void*)&bsum, (void*)&off,
            (void*)&cursor, (void*)&csr,
            (void*)&Ws0, (void*)&Wn0, (void*)&Ws1, (void*)&Wn1,
            (void*)&Ws2, (void*)&Wn2,
            (void*)&Wt0, (void*)&Wt1, (void*)&Wt2s, (void*)&Wt2n };
        hipError_t ce = hipLaunchCooperativeKernel(k_prep, dim3(1024), dim3(256),
                                                   cargs, 0, stream);
        if (ce != hipSuccess) {
            // non-coop fallback: identical 8-dispatch prep
            k_detect<<<1, 256, 0, stream>>>(srcRaw, xr, nE, flag);
            hipError_t me = hipMemsetAsync(deg, 0, (size_t)nNodes * 4, stream);
            (void)me;
            k_count<<<edgeBlocks, 256, 0, stream>>>(dstRaw, deg, nE, nNodes, flag);
            k_bsum<<<nodeBlocks, 256, 0, stream>>>(deg, bsum, nNodes);
            k_scanb<<<1, 256, 0, stream>>>(bsum, nodeBlocks);
            k_offs<<<nodeBlocks, 256, 0, stream>>>(deg, bsum, off, cursor, nNodes);
            k_fill<<<edgeBlocks, 256, 0, stream>>>(srcRaw, dstRaw, cursor, csr, nE, nNodes, flag);
            k_buildAll<<<(294912 + 255) / 256, 256, 0, stream>>>(
                Ws0, Wn0, Ws1, Wn1, Ws2, Wn2, Wt0, Wt1, Wt2s, Wt2n, C, flag);
        }

        // ---- layer 0: x -> hA ----
        k_aggr<<<aggrBlocks, 256, 0, stream>>>(x, off, csr, hmean, nNodes, flag, 1);
        k_gemm<<<gemmBlocks, 256, 0, stream>>>(x, hmean, Wt0, b0, hA, nNodes, flag, 1);

        // ---- layer 1: hA -> hX (x buffer, x now dead) ----
        k_aggr<<<aggrBlocks, 256, 0, stream>>>(hA, off, csr, hmean, nNodes, flag, 0);
        k_gemm<<<gemmBlocks, 256, 0, stream>>>(hA, hmean, Wt1, b1, hX, nNodes, flag, 0);

        // ---- layer 2 (project-first, single hX pass):
        //      {S2 = hX@Ws2 (f32), P2 = hX@Wn2}; out = softmax(S2 + mean(P2[src]) + b2)
        k_gemm256d<<<sageBlocks, 256, 0, stream>>>(hX, Wt2s, Wt2n, S2, P2, nNodes);
        k_aggrsm<<<aggrBlocks, 256, 0, stream>>>(P2, S2, off, csr, b2, d_out,
                                                 nNodes, C, flag);
    } else {
        // ---- ws-too-small fallback: original fused path ----
        const unsigned short* xr = (const unsigned short*)x;
        k_detect<<<1, 256, 0, stream>>>(srcRaw, xr, nE, flag);
        hipError_t me = hipMemsetAsync(deg, 0, (size_t)nNodes * 4, stream);
        (void)me;
        k_count<<<edgeBlocks, 256, 0, stream>>>(dstRaw, deg, nE, nNodes, flag);
        k_bsum<<<nodeBlocks, 256, 0, stream>>>(deg, bsum, nNodes);
        k_scanb<<<1, 256, 0, stream>>>(bsum, nodeBlocks);
        k_offs<<<nodeBlocks, 256, 0, stream>>>(deg, bsum, off, cursor, nNodes);
        k_fill<<<edgeBlocks, 256, 0, stream>>>(srcRaw, dstRaw, cursor, csr, nE, nNodes, flag);
        int wtB = (256 * KTOT + 255) / 256;
        k_buildWt<false><<<wtB, 256, 0, stream>>>(Ws0, Wn0, Wt0, 256, 256, flag);
        k_buildWt<true ><<<wtB, 256, 0, stream>>>(Ws0, Wn0, Wt0, 256, 256, flag);
        k_buildWt<false><<<wtB, 256, 0, stream>>>(Ws1, Wn1, Wt1, 256, 256, flag);
        k_buildWt<true ><<<wtB, 256, 0, stream>>>(Ws1, Wn1, Wt1, 256, 256, flag);
        int wtB2 = (64 * KTOT + 255) / 256;
        k_buildWt<false><<<wtB2, 256, 0, stream>>>(Ws2, Wn2, Wt2, C, 64, flag);
        k_buildWt<true ><<<wtB2, 256, 0, stream>>>(Ws2, Wn2, Wt2, C, 64, flag);
        k_sage<16, 0, false, false, false><<<sageBlocks, 256, 0, stream>>>(
            x, off, csr, Wt0, b0, hA, nNodes, 256, flag, 1);
        k_sage<16, 0, true, true, false><<<sageBlocks, 256, 0, stream>>>(
            x, off, csr, Wt0, b0, hA, nNodes, 256, flag, 0);
        k_sage<16, 0, false, false, false><<<sageBlocks, 256, 0, stream>>>(
            hA, off, csr, Wt1, b1, hX, nNodes, 256, flag, 1);
        k_sage<16, 0, false, true, false><<<sageBlocks, 256, 0, stream>>>(
            hA, off, csr, Wt1, b1, hX, nNodes, 256, flag, 0);
        k_sage<4, 1, false, false, false><<<sageBlocks, 256, 0, stream>>>(
            hX, off, csr, Wt2, b2, d_out, nNodes, C, flag, 1);
        k_sage<4, 1, false, true, true><<<sageBlocks, 256, 0, stream>>>(
            hX, off, csr, Wt2, b2, d_out, nNodes, C, flag, 0);
    }
}

// Round 12
// 563.831 us; speedup vs baseline: 1.9351x; 1.9351x over previous
//
#include <hip/hip_runtime.h>
#include <math.h>

#define FEATS 256
#define KTOT  512
#define MS    264   // meanS LDS row stride (elems) -- fallback fused kernel only
#define SA    40    // As/Bs LDS row stride (elems), 80B, 16B-aligned

typedef __attribute__((ext_vector_type(8))) __bf16 bf16x8;
typedef __attribute__((ext_vector_type(4))) float f32x4;

// async global->LDS 16B: dest = wave-uniform base + lane*16 (lane-linear)
#define ASYNC16(G, L) __builtin_amdgcn_global_load_lds( \
    (const __attribute__((address_space(1))) unsigned int*)(G), \
    (__attribute__((address_space(3))) unsigned int*)(L), 16, 0, 0)

__device__ __forceinline__ float bf2f(unsigned short u) {
    union { unsigned int i; float f; } v; v.i = ((unsigned int)u) << 16; return v.f;
}
__device__ __forceinline__ unsigned short f2bf(float f) {
    unsigned int u = __float_as_uint(f);
    unsigned int r = (u + 0x7FFFu + ((u >> 16) & 1u)) >> 16;
    return (unsigned short)r;
}
// read weight elem as bf16 from either dtype
__device__ __forceinline__ unsigned short rdw(const void* W, size_t i, bool f32m) {
    return f32m ? f2bf(((const float*)W)[i]) : ((const unsigned short*)W)[i];
}

// ---- detect: flag[0]=1 if indices are int64-strided; flag[1]=1 if floats are bf16 ----
__global__ void k_detect(const int* __restrict__ srcRaw, const unsigned short* __restrict__ xr,
                         int nE, int* __restrict__ flag) {
    __shared__ int any, cnt;
    if (threadIdx.x == 0) { any = 0; cnt = 0; }
    __syncthreads();
    int lim = nE < 1024 ? nE : 1024;
    for (int i = threadIdx.x; i < lim; i += 256)
        if (srcRaw[2 * i + 1] != 0) atomicAdd(&any, 1);
    int loc = 0;
    for (int i = threadIdx.x; i < 1024; i += 256) {
        unsigned e = (xr[2 * i] >> 7) & 255u;
        if (e >= 90u && e <= 140u) loc++;
    }
    atomicAdd(&cnt, loc);
    __syncthreads();
    if (threadIdx.x == 0) {
        flag[0] = (any == 0) ? 1 : 0;
        flag[1] = (cnt > 512) ? 1 : 0;
    }
}

__global__ void k_count(const int* __restrict__ dstRaw, int* __restrict__ deg, int nE,
                        int nNodes, const int* __restrict__ flag) {
    int e = blockIdx.x * 256 + threadIdx.x;
    if (e >= nE) return;
    int f = flag[0];
    int d = dstRaw[f ? (2 * e) : e];
    if ((unsigned)d >= (unsigned)nNodes) d = 0;
    atomicAdd(&deg[d], 1);
}

__global__ __launch_bounds__(256) void k_bsum(const int* __restrict__ deg, int* __restrict__ bsum,
                                              int n) {
    __shared__ int buf[256];
    const int t = threadIdx.x;
    int i = blockIdx.x * 256 + t;
    buf[t] = (i < n) ? deg[i] : 0;
    __syncthreads();
    for (int s = 128; s > 0; s >>= 1) {
        if (t < s) buf[t] += buf[t + s];
        __syncthreads();
    }
    if (t == 0) bsum[blockIdx.x] = buf[0];
}

__global__ __launch_bounds__(256) void k_scanb(int* __restrict__ bsum, int nB) {
    __shared__ int buf[256];
    __shared__ int carry;
    const int t = threadIdx.x;
    if (t == 0) carry = 0;
    __syncthreads();
    for (int base = 0; base < nB; base += 256) {
        int i = base + t;
        int v = (i < nB) ? bsum[i] : 0;
        buf[t] = v;
        __syncthreads();
        for (int s = 1; s < 256; s <<= 1) {
            int tv = (t >= s) ? buf[t - s] : 0;
            __syncthreads();
            buf[t] += tv;
            __syncthreads();
        }
        int exc = buf[t] - v;
        int c = carry;
        if (i < nB) bsum[i] = c + exc;
        int tot = buf[255];
        __syncthreads();
        if (t == 0) carry = c + tot;
        __syncthreads();
    }
}

__global__ __launch_bounds__(256) void k_offs(const int* __restrict__ deg,
                                              const int* __restrict__ bsum,
                                              int* __restrict__ off, int* __restrict__ cursor,
                                              int n) {
    __shared__ int buf[256];
    const int t = threadIdx.x, b = blockIdx.x;
    int i = b * 256 + t;
    int v = (i < n) ? deg[i] : 0;
    buf[t] = v;
    __syncthreads();
    for (int s = 1; s < 256; s <<= 1) {
        int tv = (t >= s) ? buf[t - s] : 0;
        __syncthreads();
        buf[t] += tv;
        __syncthreads();
    }
    int exc = bsum[b] + buf[t] - v;
    if (i < n) { off[i] = exc; cursor[i] = exc; }
    if (i == n - 1) off[n] = exc + v;
}

__global__ void k_fill(const int* __restrict__ srcRaw, const int* __restrict__ dstRaw,
                       int* __restrict__ cursor, int* __restrict__ csr, int nE,
                       int nNodes, const int* __restrict__ flag) {
    int e = blockIdx.x * 256 + threadIdx.x;
    if (e >= nE) return;
    int f = flag[0];
    int d = dstRaw[f ? (2 * e) : e];
    int s = srcRaw[f ? (2 * e) : e];
    if ((unsigned)d >= (unsigned)nNodes) d = 0;
    if ((unsigned)s >= (unsigned)nNodes) s = 0;
    int pos = atomicAdd(&cursor[d], 1);
    csr[pos] = s;
}

// ---- consolidated weight transpose: Wt0, Wt1 (256x512 combined) +
//      Wt2s, Wt2n (64x256 single), runtime dtype from flag. 1 launch. ----
__global__ __launch_bounds__(256) void k_buildAll(
        const void* __restrict__ Ws0, const void* __restrict__ Wn0,
        const void* __restrict__ Ws1, const void* __restrict__ Wn1,
        const void* __restrict__ Ws2, const void* __restrict__ Wn2,
        unsigned short* __restrict__ Wt0, unsigned short* __restrict__ Wt1,
        unsigned short* __restrict__ Wt2s, unsigned short* __restrict__ Wt2n,
        int C, const int* __restrict__ flag) {
    const bool f32m = (flag[1] == 0);
    int idx = blockIdx.x * 256 + threadIdx.x;
    if (idx < 262144) {                       // Wt0 / Wt1: n<256, k<512
        const bool one = idx >= 131072;
        int j = one ? idx - 131072 : idx;
        int n = j >> 9, k = j & 511;
        const void* Ws = one ? Ws1 : Ws0;
        const void* Wn = one ? Wn1 : Wn0;
        unsigned short v = (k < 256) ? rdw(Ws, (size_t)k * 256 + n, f32m)
                                     : rdw(Wn, (size_t)(k - 256) * 256 + n, f32m);
        (one ? Wt1 : Wt0)[j] = v;
    } else if (idx < 294912) {                // Wt2s / Wt2n: n<64 pad, k<256
        const bool nw = idx >= 278528;
        int j = nw ? idx - 278528 : idx - 262144;
        int n = j >> 8, k = j & 255;
        unsigned short v = 0;
        if (n < C) v = rdw(nw ? Wn2 : Ws2, (size_t)k * C + n, f32m);
        (nw ? Wt2n : Wt2s)[j] = v;
    }
}

// =====================================================================
// Proven aggregator (121 us @ 3.37 TB/s roofline for random 512B
// gathers): wave per row, zero LDS. Runtime dtype branch.
// =====================================================================
__global__ __launch_bounds__(256) void k_aggr(
        const void* __restrict__ h, const int* __restrict__ off,
        const int* __restrict__ csr, unsigned short* __restrict__ hmean,
        int M, const int* __restrict__ flag, int maybeF32) {
    const bool f32m = maybeF32 && (flag[1] == 0);
    const int lane = threadIdx.x & 63;
    const int wid = (blockIdx.x * 256 + threadIdx.x) >> 6;
    const int nw = (gridDim.x * 256) >> 6;
    if (f32m) {
        for (int r = wid; r < M; r += nw) {
            const int e0 = off[r], e1 = off[r + 1];
            float a0 = 0.f, a1 = 0.f, a2 = 0.f, a3 = 0.f;
            for (int base = e0; base < e1; base += 64) {
                int cnt = e1 - base; if (cnt > 64) cnt = 64;
                int sidx = (lane < cnt) ? csr[base + lane] : 0;
                #pragma unroll 8
                for (int d = 0; d < cnt; d++) {
                    int s = __shfl(sidx, d);
                    float4 hv = reinterpret_cast<const float4*>(
                        (const float*)h + (size_t)s * FEATS)[lane];
                    a0 += hv.x; a1 += hv.y; a2 += hv.z; a3 += hv.w;
                }
            }
            float rc = 1.0f / fmaxf((float)(e1 - e0), 1.0f);
            ushort4 o;
            o.x = f2bf(a0 * rc); o.y = f2bf(a1 * rc); o.z = f2bf(a2 * rc); o.w = f2bf(a3 * rc);
            *reinterpret_cast<ushort4*>(&hmean[(size_t)r * FEATS + lane * 4]) = o;
        }
    } else {
        for (int r = wid; r < M; r += nw) {
            const int e0 = off[r], e1 = off[r + 1];
            float a0 = 0.f, a1 = 0.f, a2 = 0.f, a3 = 0.f;
            for (int base = e0; base < e1; base += 64) {
                int cnt = e1 - base; if (cnt > 64) cnt = 64;
                int sidx = (lane < cnt) ? csr[base + lane] : 0;
                #pragma unroll 8
                for (int d = 0; d < cnt; d++) {
                    int s = __shfl(sidx, d);
                    ushort4 hv = reinterpret_cast<const ushort4*>(
                        (const unsigned short*)h + (size_t)s * FEATS)[lane];
                    a0 += bf2f(hv.x); a1 += bf2f(hv.y); a2 += bf2f(hv.z); a3 += bf2f(hv.w);
                }
            }
            float rc = 1.0f / fmaxf((float)(e1 - e0), 1.0f);
            ushort4 o;
            o.x = f2bf(a0 * rc); o.y = f2bf(a1 * rc); o.z = f2bf(a2 * rc); o.w = f2bf(a3 * rc);
            *reinterpret_cast<ushort4*>(&hmean[(size_t)r * FEATS + lane * 4]) = o;
        }
    }
}

// =====================================================================
// Lean GEMM (layers 0/1): 64 rows x 128 cols per block, BK=64,
// global_load_lds width-16 into linear LDS with chunk^(row&7) swizzle.
// NEW (r12): 2-phase double-buffered pipeline — issue next K-tile's
// global_load_lds BEFORE computing the current tile; single barrier
// per step drains vmcnt. LDS 48 KB (3 blk/CU).
// =====================================================================
__global__ __launch_bounds__(256) void k_gemm(
        const void* __restrict__ h, const unsigned short* __restrict__ hmean,
        const unsigned short* __restrict__ Wt, const void* __restrict__ bias,
        void* __restrict__ out, int M, const int* __restrict__ flag, int maybeF32) {
    const bool inF32 = (flag[1] == 0);
    const bool hF32 = maybeF32 && inF32;
    __shared__ __align__(16) unsigned short As[2][64 * 64];    // 16 KB
    __shared__ __align__(16) unsigned short Bs[2][128 * 64];   // 32 KB

    const int rb = (int)blockIdx.x >> 1;
    const int chalf = (int)blockIdx.x & 1;
    const int m0 = rb * 64;
    const int col0 = chalf * 128;
    const int tid = threadIdx.x;
    const int lane = tid & 63, w = tid >> 6;
    const int nh = lane & 15, q = lane >> 4;   // q in 0..3

    f32x4 acc[8];
    #pragma unroll
    for (int ci = 0; ci < 8; ci++) acc[ci] = (f32x4){0.f, 0.f, 0.f, 0.f};

    auto stageAB = [&](int bsel, int kb) {
        #pragma unroll
        for (int j = 0; j < 2; j++) {
            int t2 = tid + j * 256;
            int row = t2 >> 3, c = t2 & 7;
            int gr = m0 + row; if (gr > M - 1) gr = M - 1;
            int cs = c ^ (row & 7);            // pre-swizzled source chunk
            if (kb < 256) {
                if (hF32) {
                    const float* p = (const float*)h + (size_t)gr * FEATS + kb + cs * 8;
                    float4 a = *reinterpret_cast<const float4*>(p);
                    float4 b = *reinterpret_cast<const float4*>(p + 4);
                    unsigned short* d = &As[bsel][t2 * 8];
                    d[0]=f2bf(a.x); d[1]=f2bf(a.y); d[2]=f2bf(a.z); d[3]=f2bf(a.w);
                    d[4]=f2bf(b.x); d[5]=f2bf(b.y); d[6]=f2bf(b.z); d[7]=f2bf(b.w);
                } else {
                    ASYNC16((const unsigned short*)h + (size_t)gr * FEATS + kb + cs * 8,
                            &As[bsel][t2 * 8]);
                }
            } else {
                ASYNC16(hmean + (size_t)gr * FEATS + (kb - 256) + cs * 8, &As[bsel][t2 * 8]);
            }
        }
        #pragma unroll
        for (int j = 0; j < 4; j++) {
            int t2 = tid + j * 256;
            int n = t2 >> 3, c = t2 & 7;
            int cs = c ^ (n & 7);
            ASYNC16(Wt + (size_t)(col0 + n) * KTOT + kb + cs * 8, &Bs[bsel][t2 * 8]);
        }
    };

    // prologue: stage tile 0, drain, then pipeline
    stageAB(0, 0);
    __syncthreads();
    int cur = 0;
    for (int kb = 0; kb < KTOT; kb += 64) {
        if (kb + 64 < KTOT) stageAB(cur ^ 1, kb + 64);   // issue next tile's loads
        #pragma unroll
        for (int s = 0; s < 2; s++) {
            const int arow = w * 16 + nh;
            const int qa = ((s * 4 + q) ^ (arow & 7));
            bf16x8 afr = *reinterpret_cast<const bf16x8*>(&As[cur][arow * 64 + qa * 8]);
            #pragma unroll
            for (int ci = 0; ci < 8; ci++) {
                int n = ci * 16 + nh;
                int qb = ((s * 4 + q) ^ (n & 7));
                bf16x8 bfr = *reinterpret_cast<const bf16x8*>(&Bs[cur][n * 64 + qb * 8]);
                acc[ci] = __builtin_amdgcn_mfma_f32_16x16x32_bf16(afr, bfr, acc[ci], 0, 0, 0);
            }
        }
        __syncthreads();   // drains vmcnt: next buffer ready; this buffer free
        cur ^= 1;
    }

    const int rbase = m0 + w * 16 + q * 4;
    const float sc = 1.0507009873554805f, al = 1.6732632423543772f;
    #pragma unroll
    for (int ci = 0; ci < 8; ci++) {
        int col = col0 + ci * 16 + nh;
        float b = inF32 ? ((const float*)bias)[col] : bf2f(((const unsigned short*)bias)[col]);
        #pragma unroll
        for (int rg = 0; rg < 4; rg++) {
            int r = rbase + rg;
            if (r < M) {
                float v = acc[ci][rg] + b;
                v = (v > 0.f) ? sc * v : sc * al * expm1f(v);
                ((unsigned short*)out)[(size_t)r * FEATS + col] = f2bf(v);
            }
        }
    }
}

// =====================================================================
// Layer-2 dual GEMM (single hX pass): S2 = hX @ Ws2 (f32, stride 64)
// AND P2 = hX @ Wn2 (bf16, stride 64). 64 rows x 128 cols, K=256.
// =====================================================================
__global__ __launch_bounds__(256) void k_gemm256d(
        const unsigned short* __restrict__ h, const unsigned short* __restrict__ Wt2s,
        const unsigned short* __restrict__ Wt2n, float* __restrict__ S2,
        unsigned short* __restrict__ P2, int M) {
    __shared__ __align__(16) unsigned short As[64 * SA];
    __shared__ __align__(16) unsigned short Bs[128 * SA];

    const int m0 = blockIdx.x * 64;
    const int tid = threadIdx.x;
    const int lane = tid & 63, w = tid >> 6;
    const int nh = lane & 15, q = lane >> 4;

    f32x4 acc[8];
    #pragma unroll
    for (int ci = 0; ci < 8; ci++) acc[ci] = (f32x4){0.f, 0.f, 0.f, 0.f};

    for (int kb = 0; kb < 256; kb += 32) {
        {
            int row = tid >> 2, seg = tid & 3;
            int gr = m0 + row; if (gr > M - 1) gr = M - 1;
            *reinterpret_cast<float4*>(&As[row * SA + seg * 8]) =
                *reinterpret_cast<const float4*>(h + (size_t)gr * FEATS + kb + seg * 8);
        }
        for (int u = tid; u < 128 * 4; u += 256) {
            int nn = u >> 2, seg = u & 3;
            const unsigned short* src = (nn < 64)
                ? Wt2s + (size_t)nn * 256 : Wt2n + (size_t)(nn - 64) * 256;
            *reinterpret_cast<float4*>(&Bs[nn * SA + seg * 8]) =
                *reinterpret_cast<const float4*>(src + kb + seg * 8);
        }
        __syncthreads();
        bf16x8 afr = *reinterpret_cast<const bf16x8*>(&As[(w * 16 + nh) * SA + q * 8]);
        #pragma unroll
        for (int ci = 0; ci < 8; ci++) {
            bf16x8 bfr = *reinterpret_cast<const bf16x8*>(&Bs[(ci * 16 + nh) * SA + q * 8]);
            acc[ci] = __builtin_amdgcn_mfma_f32_16x16x32_bf16(afr, bfr, acc[ci], 0, 0, 0);
        }
        __syncthreads();
    }

    const int rbase = m0 + w * 16 + q * 4;
    #pragma unroll
    for (int ci = 0; ci < 4; ci++) {       // self half -> S2 (f32)
        int col = ci * 16 + nh;
        #pragma unroll
        for (int rg = 0; rg < 4; rg++) {
            int r = rbase + rg;
            if (r < M) S2[(size_t)r * 64 + col] = acc[ci][rg];
        }
    }
    #pragma unroll
    for (int ci = 4; ci < 8; ci++) {       // neigh half -> P2 (bf16)
        int col = (ci - 4) * 16 + nh;
        #pragma unroll
        for (int rg = 0; rg < 4; rg++) {
            int r = rbase + rg;
            if (r < M) P2[(size_t)r * 64 + col] = f2bf(acc[ci][rg]);
        }
    }
}

// =====================================================================
// FUSED layer-2 tail: gather-mean of P2 (wave per row, 2 grp x 32 ln)
// + softmax(S2 + mean + b2) in-register. Full-exec shuffles (r11 fix,
// verified): divergent ds_bpermute from inactive lanes returns 0.
// =====================================================================
__global__ __launch_bounds__(256) void k_aggrsm(
        const unsigned short* __restrict__ P, const float* __restrict__ S2,
        const int* __restrict__ off, const int* __restrict__ csr,
        const void* __restrict__ bias, void* __restrict__ out,
        int M, int C, const int* __restrict__ flag) {
    const bool inF32 = (flag[1] == 0);
    const int lane = threadIdx.x & 63;
    const int wid = (blockIdx.x * 256 + threadIdx.x) >> 6;
    const int nw = (gridDim.x * 256) >> 6;
    const int g = lane >> 5, li = lane & 31;
    for (int r = wid; r < M; r += nw) {
        const int e0 = off[r], e1 = off[r + 1];
        float a0 = 0.f, a1 = 0.f;
        #pragma unroll 4
        for (int base = e0; base < e1; base += 2) {
            int e = base + g;
            if (e < e1) {
                int s = csr[e];
                ushort2 hv = *reinterpret_cast<const ushort2*>(
                    P + (size_t)s * 64 + li * 2);
                a0 += bf2f(hv.x); a1 += bf2f(hv.y);
            }
        }
        a0 += __shfl_xor(a0, 32); a1 += __shfl_xor(a1, 32);   // all lanes hold totals
        float rc = 1.0f / fmaxf((float)(e1 - e0), 1.0f);
        // redistribute with FULL exec mask, then select
        float av0 = __shfl(a0, lane >> 1);
        float av1 = __shfl(a1, lane >> 1);
        float av = (lane & 1) ? av1 : av0;
        float v = -1e30f;
        if (lane < C) {
            float b = inF32 ? ((const float*)bias)[lane]
                            : bf2f(((const unsigned short*)bias)[lane]);
            v = S2[(size_t)r * 64 + lane] + av * rc + b;
        }
        float mx = v;
        #pragma unroll
        for (int mk = 1; mk <= 32; mk <<= 1) mx = fmaxf(mx, __shfl_xor(mx, mk));
        float e = (lane < C) ? __expf(v - mx) : 0.f;
        float s = e;
        #pragma unroll
        for (int mk = 1; mk <= 32; mk <<= 1) s += __shfl_xor(s, mk);
        float o = e / s;
        if (lane < C) {
            if (inF32) ((float*)out)[(size_t)r * C + lane] = o;
            else ((unsigned short*)out)[(size_t)r * C + lane] = f2bf(o);
        }
    }
}

// =====================================================================
// FALLBACK path kernels (workspace too small): original fused kernel +
// dual-dtype weight transpose. Verified-correct from earlier sessions.
// =====================================================================
template <bool F32>
__global__ void k_buildWt(const void* __restrict__ Ws, const void* __restrict__ Wn,
                          unsigned short* __restrict__ Wt, int N, int Npad,
                          const int* __restrict__ flag) {
    if (flag[1] != (F32 ? 0 : 1)) return;
    int idx = blockIdx.x * 256 + threadIdx.x;
    if (idx >= Npad * KTOT) return;
    int n = idx >> 9, k = idx & 511;
    unsigned short v = 0;
    if (n < N) {
        if (F32) {
            float fv = (k < 256) ? ((const float*)Ws)[k * N + n]
                                 : ((const float*)Wn)[(k - 256) * N + n];
            v = f2bf(fv);
        } else {
            v = (k < 256) ? ((const unsigned short*)Ws)[k * N + n]
                          : ((const unsigned short*)Wn)[(k - 256) * N + n];
        }
    }
    Wt[idx] = v;
}

template <bool F32>
__device__ __forceinline__ void stage8(const void* h, size_t elemOff, unsigned short* dst) {
    if (!F32) {
        *reinterpret_cast<float4*>(dst) =
            *reinterpret_cast<const float4*>((const unsigned short*)h + elemOff);
    } else {
        const float* p = (const float*)h + elemOff;
        float4 a = *reinterpret_cast<const float4*>(p);
        float4 b = *reinterpret_cast<const float4*>(p + 4);
        dst[0] = f2bf(a.x); dst[1] = f2bf(a.y); dst[2] = f2bf(a.z); dst[3] = f2bf(a.w);
        dst[4] = f2bf(b.x); dst[5] = f2bf(b.y); dst[6] = f2bf(b.z); dst[7] = f2bf(b.w);
    }
}

template <int NT, int ACT, bool HF32, bool BF32, bool OF32>
__global__ __launch_bounds__(256) void k_sage(
        const void* __restrict__ h, const int* __restrict__ off,
        const int* __restrict__ csr, const unsigned short* __restrict__ Wt,
        const void* __restrict__ bias, void* __restrict__ out,
        int M, int C, const int* __restrict__ flag, int want) {
    if (flag[1] != want) return;
    __shared__ __align__(16) unsigned short meanS[64 * MS];
    __shared__ __align__(16) unsigned short As[64 * SA];
    __shared__ __align__(16) unsigned short Bs[NT * 16 * SA];

    const int m0 = blockIdx.x * 64;
    const int tid = threadIdx.x;
    const int lane = tid & 63, w = tid >> 6;
    const int nh = lane & 15, q = lane >> 4;

    for (int i = 0; i < 16; i++) {
        int lr = w * 16 + i;
        int r = m0 + lr;
        int rr = (r < M) ? r : (M - 1);
        int e0 = off[rr], e1 = off[rr + 1];
        float a0 = 0.f, a1 = 0.f, a2 = 0.f, a3 = 0.f;
        #pragma unroll 8
        for (int j = e0; j < e1; j++) {
            int s = csr[j];
            if (HF32) {
                float4 hv = reinterpret_cast<const float4*>((const float*)h + (size_t)s * FEATS)[lane];
                a0 += hv.x; a1 += hv.y; a2 += hv.z; a3 += hv.w;
            } else {
                ushort4 hv = reinterpret_cast<const ushort4*>((const unsigned short*)h + (size_t)s * FEATS)[lane];
                a0 += bf2f(hv.x); a1 += bf2f(hv.y); a2 += bf2f(hv.z); a3 += bf2f(hv.w);
            }
        }
        float rc = 1.0f / fmaxf((float)(e1 - e0), 1.0f);
        ushort4 o;
        o.x = f2bf(a0 * rc); o.y = f2bf(a1 * rc); o.z = f2bf(a2 * rc); o.w = f2bf(a3 * rc);
        *reinterpret_cast<ushort4*>(&meanS[lr * MS + lane * 4]) = o;
    }
    __syncthreads();

    f32x4 acc[NT];
    #pragma unroll
    for (int ci = 0; ci < NT; ci++) acc[ci] = (f32x4){0.f, 0.f, 0.f, 0.f};

    for (int kb = 0; kb < KTOT; kb += 32) {
        const bool fromMean = (kb >= 256);
        if (!fromMean) {
            int row = tid >> 2, seg = tid & 3;
            int gr = m0 + row; if (gr > M - 1) gr = M - 1;
            stage8<HF32>(h, (size_t)gr * FEATS + kb + seg * 8, &As[row * SA + seg * 8]);
        }
        for (int u = tid; u < NT * 64; u += 256) {
            int nn = u >> 2, seg = u & 3;
            *reinterpret_cast<float4*>(&Bs[nn * SA + seg * 8]) =
                *reinterpret_cast<const float4*>(Wt + (size_t)nn * KTOT + kb + seg * 8);
        }
        __syncthreads();
        bf16x8 afr;
        if (!fromMean)
            afr = *reinterpret_cast<const bf16x8*>(&As[(w * 16 + nh) * SA + q * 8]);
        else
            afr = *reinterpret_cast<const bf16x8*>(&meanS[(w * 16 + nh) * MS + (kb - 256) + q * 8]);
        #pragma unroll
        for (int ci = 0; ci < NT; ci++) {
            bf16x8 bfr = *reinterpret_cast<const bf16x8*>(&Bs[(ci * 16 + nh) * SA + q * 8]);
            acc[ci] = __builtin_amdgcn_mfma_f32_16x16x32_bf16(afr, bfr, acc[ci], 0, 0, 0);
        }
        __syncthreads();
    }

    const int rbase = m0 + w * 16 + q * 4;
    if (ACT == 0) {
        const float sc = 1.0507009873554805f, al = 1.6732632423543772f;
        #pragma unroll
        for (int ci = 0; ci < NT; ci++) {
            int col = ci * 16 + nh;
            float b = BF32 ? ((const float*)bias)[col] : bf2f(((const unsigned short*)bias)[col]);
            #pragma unroll
            for (int rg = 0; rg < 4; rg++) {
                int r = rbase + rg;
                if (r < M) {
                    float v = acc[ci][rg] + b;
                    v = (v > 0.f) ? sc * v : sc * al * expm1f(v);
                    if (OF32) ((float*)out)[(size_t)r * (NT * 16) + col] = v;
                    else ((unsigned short*)out)[(size_t)r * (NT * 16) + col] = f2bf(v);
                }
            }
        }
    } else {
        #pragma unroll
        for (int rg = 0; rg < 4; rg++) {
            int r = rbase + rg;
            float vals[NT];
            float mx = -1e30f;
            #pragma unroll
            for (int ci = 0; ci < NT; ci++) {
                int col = ci * 16 + nh;
                float v = -1e30f;
                if (col < C) {
                    float b = BF32 ? ((const float*)bias)[col] : bf2f(((const unsigned short*)bias)[col]);
                    v = acc[ci][rg] + b;
                }
                vals[ci] = v;
                mx = fmaxf(mx, v);
            }
            #pragma unroll
            for (int mk = 1; mk <= 8; mk <<= 1) mx = fmaxf(mx, __shfl_xor(mx, mk));
            float s = 0.f;
            #pragma unroll
            for (int ci = 0; ci < NT; ci++) {
                float e = (vals[ci] <= -1e29f) ? 0.f : __expf(vals[ci] - mx);
                vals[ci] = e; s += e;
            }
            #pragma unroll
            for (int mk = 1; mk <= 8; mk <<= 1) s += __shfl_xor(s, mk);
            float inv = 1.f / s;
            if (r < M) {
                #pragma unroll
                for (int ci = 0; ci < NT; ci++) {
                    int col = ci * 16 + nh;
                    if (col < C) {
                        if (OF32) ((float*)out)[(size_t)r * C + col] = vals[ci] * inv;
                        else ((unsigned short*)out)[(size_t)r * C + col] = f2bf(vals[ci] * inv);
                    }
                }
            }
        }
    }
}

extern "C" void kernel_launch(void* const* d_in, const int* in_sizes, int n_in,
                              void* d_out, int out_size, void* d_ws, size_t ws_size,
                              hipStream_t stream) {
    const int* srcRaw = (const int*)d_in[1];
    const int* dstRaw = (const int*)d_in[2];
    const void* x   = d_in[0];
    const void* Ws0 = d_in[3]; const void* Wn0 = d_in[4]; const void* b0 = d_in[5];
    const void* Ws1 = d_in[6]; const void* Wn1 = d_in[7]; const void* b1 = d_in[8];
    const void* Ws2 = d_in[9]; const void* Wn2 = d_in[10]; const void* b2 = d_in[11];

    const int nNodes = in_sizes[0] / FEATS;   // 50000
    const int nE     = in_sizes[1];           // 800000
    const int C      = in_sizes[11];          // 47

    // ---- workspace carve ----
    char* ws = (char*)d_ws;
    size_t off_b = 0;
    auto carve = [&](size_t bytes) -> void* {
        void* p = (void*)(ws + off_b);
        off_b += (bytes + 255) & ~(size_t)255;
        return p;
    };
    int*            flag   = (int*)           carve(256);
    int*            deg    = (int*)           carve((size_t)nNodes * 4);
    int*            cursor = (int*)           carve((size_t)nNodes * 4);
    int*            off    = (int*)           carve((size_t)(nNodes + 1) * 4);
    int*            csr    = (int*)           carve((size_t)nE * 4);
    unsigned short* Wt0    = (unsigned short*)carve((size_t)256 * KTOT * 2);
    unsigned short* Wt1    = (unsigned short*)carve((size_t)256 * KTOT * 2);
    unsigned short* Wt2    = (unsigned short*)carve((size_t)64 * KTOT * 2);   // fallback combined
    unsigned short* Wt2s   = (unsigned short*)carve((size_t)64 * 256 * 2);
    unsigned short* Wt2n   = (unsigned short*)carve((size_t)64 * 256 * 2);
    int*            bsum   = (int*)           carve(4096);
    unsigned short* hA     = (unsigned short*)carve((size_t)nNodes * FEATS * 2);
    unsigned short* hmean  = (unsigned short*)carve((size_t)nNodes * FEATS * 2);
    const bool split = (off_b <= ws_size);
    // layer-2 buffers tile into hmean (dead for layer 2):
    //   S2 f32 (nN*64*4 B) | P2 bf16 (nN*64*2 B)
    const size_t l2n = (size_t)nNodes * 64;
    float*          S2 = (float*)hmean;                 // bytes [0, 4*l2n)
    unsigned short* P2 = hmean + l2n * 2;               // bytes [4*l2n, 6*l2n)
    // h2 lives in the (dead-after-layer-0, harness-restored) x input buffer
    unsigned short* hX = (unsigned short*)d_in[0];

    const int edgeBlocks = (nE + 255) / 256;
    const int nodeBlocks = (nNodes + 255) / 256;   // 196 <= 1024
    const int sageBlocks = (nNodes + 63) / 64;     // 782
    const int gemmBlocks = sageBlocks * 2;         // 64x128 tiles, col-half split
    const int aggrBlocks = 2048;

    // ---- prep: detect + CSR build + weight transposes (proven 8-dispatch) ----
    const unsigned short* xr = (const unsigned short*)x;
    k_detect<<<1, 256, 0, stream>>>(srcRaw, xr, nE, flag);
    hipError_t me = hipMemsetAsync(deg, 0, (size_t)nNodes * 4, stream);
    (void)me;
    k_count<<<edgeBlocks, 256, 0, stream>>>(dstRaw, deg, nE, nNodes, flag);
    k_bsum<<<nodeBlocks, 256, 0, stream>>>(deg, bsum, nNodes);
    k_scanb<<<1, 256, 0, stream>>>(bsum, nodeBlocks);
    k_offs<<<nodeBlocks, 256, 0, stream>>>(deg, bsum, off, cursor, nNodes);
    k_fill<<<edgeBlocks, 256, 0, stream>>>(srcRaw, dstRaw, cursor, csr, nE, nNodes, flag);

    if (split) {
        k_buildAll<<<(294912 + 255) / 256, 256, 0, stream>>>(
            Ws0, Wn0, Ws1, Wn1, Ws2, Wn2, Wt0, Wt1, Wt2s, Wt2n, C, flag);

        // ---- layer 0: x -> hA ----
        k_aggr<<<aggrBlocks, 256, 0, stream>>>(x, off, csr, hmean, nNodes, flag, 1);
        k_gemm<<<gemmBlocks, 256, 0, stream>>>(x, hmean, Wt0, b0, hA, nNodes, flag, 1);

        // ---- layer 1: hA -> hX (x buffer, x now dead) ----
        k_aggr<<<aggrBlocks, 256, 0, stream>>>(hA, off, csr, hmean, nNodes, flag, 0);
        k_gemm<<<gemmBlocks, 256, 0, stream>>>(hA, hmean, Wt1, b1, hX, nNodes, flag, 0);

        // ---- layer 2 (project-first, single hX pass):
        //      {S2 = hX@Ws2 (f32), P2 = hX@Wn2}; out = softmax(S2 + mean(P2[src]) + b2)
        k_gemm256d<<<sageBlocks, 256, 0, stream>>>(hX, Wt2s, Wt2n, S2, P2, nNodes);
        k_aggrsm<<<aggrBlocks, 256, 0, stream>>>(P2, S2, off, csr, b2, d_out,
                                                 nNodes, C, flag);
    } else {
        // ---- ws-too-small fallback: original fused path ----
        int wtB = (256 * KTOT + 255) / 256;
        k_buildWt<false><<<wtB, 256, 0, stream>>>(Ws0, Wn0, Wt0, 256, 256, flag);
        k_buildWt<true ><<<wtB, 256, 0, stream>>>(Ws0, Wn0, Wt0, 256, 256, flag);
        k_buildWt<false><<<wtB, 256, 0, stream>>>(Ws1, Wn1, Wt1, 256, 256, flag);
        k_buildWt<true ><<<wtB, 256, 0, stream>>>(Ws1, Wn1, Wt1, 256, 256, flag);
        int wtB2 = (64 * KTOT + 255) / 256;
        k_buildWt<false><<<wtB2, 256, 0, stream>>>(Ws2, Wn2, Wt2, C, 64, flag);
        k_buildWt<true ><<<wtB2, 256, 0, stream>>>(Ws2, Wn2, Wt2, C, 64, flag);
        k_sage<16, 0, false, false, false><<<sageBlocks, 256, 0, stream>>>(
            x, off, csr, Wt0, b0, hA, nNodes, 256, flag, 1);
        k_sage<16, 0, true, true, false><<<sageBlocks, 256, 0, stream>>>(
            x, off, csr, Wt0, b0, hA, nNodes, 256, flag, 0);
        k_sage<16, 0, false, false, false><<<sageBlocks, 256, 0, stream>>>(
            hA, off, csr, Wt1, b1, hX, nNodes, 256, flag, 1);
        k_sage<16, 0, false, true, false><<<sageBlocks, 256, 0, stream>>>(
            hA, off, csr, Wt1, b1, hX, nNodes, 256, flag, 0);
        k_sage<4, 1, false, false, false><<<sageBlocks, 256, 0, stream>>>(
            hX, off, csr, Wt2, b2, d_out, nNodes, C, flag, 1);
        k_sage<4, 1, false, true, true><<<sageBlocks, 256, 0, stream>>>(
            hX, off, csr, Wt2, b2, d_out, nNodes, C, flag, 0);
    }
}

// Round 14
// 536.766 us; speedup vs baseline: 2.0326x; 1.0504x over previous
//
#include <hip/hip_runtime.h>
#include <math.h>

#define FEATS 256
#define KTOT  512
#define MS    264   // meanS LDS row stride (elems) -- fallback fused kernel only
#define SA    40    // As/Bs LDS row stride (elems), 80B, 16B-aligned

typedef __attribute__((ext_vector_type(8))) __bf16 bf16x8;
typedef __attribute__((ext_vector_type(4))) float f32x4;

// async global->LDS 16B: dest = wave-uniform base + lane*16 (lane-linear)
#define ASYNC16(G, L) __builtin_amdgcn_global_load_lds( \
    (const __attribute__((address_space(1))) unsigned int*)(G), \
    (__attribute__((address_space(3))) unsigned int*)(L), 16, 0, 0)

__device__ __forceinline__ float bf2f(unsigned short u) {
    union { unsigned int i; float f; } v; v.i = ((unsigned int)u) << 16; return v.f;
}
__device__ __forceinline__ unsigned short f2bf(float f) {
    unsigned int u = __float_as_uint(f);
    unsigned int r = (u + 0x7FFFu + ((u >> 16) & 1u)) >> 16;
    return (unsigned short)r;
}
// read weight elem as bf16 from either dtype
__device__ __forceinline__ unsigned short rdw(const void* W, size_t i, bool f32m) {
    return f32m ? f2bf(((const float*)W)[i]) : ((const unsigned short*)W)[i];
}

// ---- detect: flag[0]=1 if indices are int64-strided; flag[1]=1 if floats are bf16 ----
__global__ void k_detect(const int* __restrict__ srcRaw, const unsigned short* __restrict__ xr,
                         int nE, int* __restrict__ flag) {
    __shared__ int any, cnt;
    if (threadIdx.x == 0) { any = 0; cnt = 0; }
    __syncthreads();
    int lim = nE < 1024 ? nE : 1024;
    for (int i = threadIdx.x; i < lim; i += 256)
        if (srcRaw[2 * i + 1] != 0) atomicAdd(&any, 1);
    int loc = 0;
    for (int i = threadIdx.x; i < 1024; i += 256) {
        unsigned e = (xr[2 * i] >> 7) & 255u;
        if (e >= 90u && e <= 140u) loc++;
    }
    atomicAdd(&cnt, loc);
    __syncthreads();
    if (threadIdx.x == 0) {
        flag[0] = (any == 0) ? 1 : 0;
        flag[1] = (cnt > 512) ? 1 : 0;
    }
}

__global__ void k_count(const int* __restrict__ dstRaw, int* __restrict__ deg, int nE,
                        int nNodes, const int* __restrict__ flag) {
    int e = blockIdx.x * 256 + threadIdx.x;
    if (e >= nE) return;
    int f = flag[0];
    int d = dstRaw[f ? (2 * e) : e];
    if ((unsigned)d >= (unsigned)nNodes) d = 0;
    atomicAdd(&deg[d], 1);
}

__global__ __launch_bounds__(256) void k_bsum(const int* __restrict__ deg, int* __restrict__ bsum,
                                              int n) {
    __shared__ int buf[256];
    const int t = threadIdx.x;
    int i = blockIdx.x * 256 + t;
    buf[t] = (i < n) ? deg[i] : 0;
    __syncthreads();
    for (int s = 128; s > 0; s >>= 1) {
        if (t < s) buf[t] += buf[t + s];
        __syncthreads();
    }
    if (t == 0) bsum[blockIdx.x] = buf[0];
}

__global__ __launch_bounds__(256) void k_scanb(int* __restrict__ bsum, int nB) {
    __shared__ int buf[256];
    __shared__ int carry;
    const int t = threadIdx.x;
    if (t == 0) carry = 0;
    __syncthreads();
    for (int base = 0; base < nB; base += 256) {
        int i = base + t;
        int v = (i < nB) ? bsum[i] : 0;
        buf[t] = v;
        __syncthreads();
        for (int s = 1; s < 256; s <<= 1) {
            int tv = (t >= s) ? buf[t - s] : 0;
            __syncthreads();
            buf[t] += tv;
            __syncthreads();
        }
        int exc = buf[t] - v;
        int c = carry;
        if (i < nB) bsum[i] = c + exc;
        int tot = buf[255];
        __syncthreads();
        if (t == 0) carry = c + tot;
        __syncthreads();
    }
}

__global__ __launch_bounds__(256) void k_offs(const int* __restrict__ deg,
                                              const int* __restrict__ bsum,
                                              int* __restrict__ off, int* __restrict__ cursor,
                                              int n) {
    __shared__ int buf[256];
    const int t = threadIdx.x, b = blockIdx.x;
    int i = b * 256 + t;
    int v = (i < n) ? deg[i] : 0;
    buf[t] = v;
    __syncthreads();
    for (int s = 1; s < 256; s <<= 1) {
        int tv = (t >= s) ? buf[t - s] : 0;
        __syncthreads();
        buf[t] += tv;
        __syncthreads();
    }
    int exc = bsum[b] + buf[t] - v;
    if (i < n) { off[i] = exc; cursor[i] = exc; }
    if (i == n - 1) off[n] = exc + v;
}

__global__ void k_fill(const int* __restrict__ srcRaw, const int* __restrict__ dstRaw,
                       int* __restrict__ cursor, int* __restrict__ csr, int nE,
                       int nNodes, const int* __restrict__ flag) {
    int e = blockIdx.x * 256 + threadIdx.x;
    if (e >= nE) return;
    int f = flag[0];
    int d = dstRaw[f ? (2 * e) : e];
    int s = srcRaw[f ? (2 * e) : e];
    if ((unsigned)d >= (unsigned)nNodes) d = 0;
    if ((unsigned)s >= (unsigned)nNodes) s = 0;
    int pos = atomicAdd(&cursor[d], 1);
    csr[pos] = s;
}

// ---- consolidated weight transpose: Wt0, Wt1 (256x512 combined) +
//      Wt2s, Wt2n (64x256 single), runtime dtype from flag. 1 launch. ----
__global__ __launch_bounds__(256) void k_buildAll(
        const void* __restrict__ Ws0, const void* __restrict__ Wn0,
        const void* __restrict__ Ws1, const void* __restrict__ Wn1,
        const void* __restrict__ Ws2, const void* __restrict__ Wn2,
        unsigned short* __restrict__ Wt0, unsigned short* __restrict__ Wt1,
        unsigned short* __restrict__ Wt2s, unsigned short* __restrict__ Wt2n,
        int C, const int* __restrict__ flag) {
    const bool f32m = (flag[1] == 0);
    int idx = blockIdx.x * 256 + threadIdx.x;
    if (idx < 262144) {                       // Wt0 / Wt1: n<256, k<512
        const bool one = idx >= 131072;
        int j = one ? idx - 131072 : idx;
        int n = j >> 9, k = j & 511;
        const void* Ws = one ? Ws1 : Ws0;
        const void* Wn = one ? Wn1 : Wn0;
        unsigned short v = (k < 256) ? rdw(Ws, (size_t)k * 256 + n, f32m)
                                     : rdw(Wn, (size_t)(k - 256) * 256 + n, f32m);
        (one ? Wt1 : Wt0)[j] = v;
    } else if (idx < 294912) {                // Wt2s / Wt2n: n<64 pad, k<256
        const bool nw = idx >= 278528;
        int j = nw ? idx - 278528 : idx - 262144;
        int n = j >> 8, k = j & 255;
        unsigned short v = 0;
        if (n < C) v = rdw(nw ? Wn2 : Ws2, (size_t)k * C + n, f32m);
        (nw ? Wt2n : Wt2s)[j] = v;
    }
}

// =====================================================================
// Proven aggregator (121 us @ 3.37 TB/s roofline for random 512B
// gathers): wave per row, zero LDS. Runtime dtype branch.
// =====================================================================
__global__ __launch_bounds__(256) void k_aggr(
        const void* __restrict__ h, const int* __restrict__ off,
        const int* __restrict__ csr, unsigned short* __restrict__ hmean,
        int M, const int* __restrict__ flag, int maybeF32) {
    const bool f32m = maybeF32 && (flag[1] == 0);
    const int lane = threadIdx.x & 63;
    const int wid = (blockIdx.x * 256 + threadIdx.x) >> 6;
    const int nw = (gridDim.x * 256) >> 6;
    if (f32m) {
        for (int r = wid; r < M; r += nw) {
            const int e0 = off[r], e1 = off[r + 1];
            float a0 = 0.f, a1 = 0.f, a2 = 0.f, a3 = 0.f;
            for (int base = e0; base < e1; base += 64) {
                int cnt = e1 - base; if (cnt > 64) cnt = 64;
                int sidx = (lane < cnt) ? csr[base + lane] : 0;
                #pragma unroll 8
                for (int d = 0; d < cnt; d++) {
                    int s = __shfl(sidx, d);
                    float4 hv = reinterpret_cast<const float4*>(
                        (const float*)h + (size_t)s * FEATS)[lane];
                    a0 += hv.x; a1 += hv.y; a2 += hv.z; a3 += hv.w;
                }
            }
            float rc = 1.0f / fmaxf((float)(e1 - e0), 1.0f);
            ushort4 o;
            o.x = f2bf(a0 * rc); o.y = f2bf(a1 * rc); o.z = f2bf(a2 * rc); o.w = f2bf(a3 * rc);
            *reinterpret_cast<ushort4*>(&hmean[(size_t)r * FEATS + lane * 4]) = o;
        }
    } else {
        for (int r = wid; r < M; r += nw) {
            const int e0 = off[r], e1 = off[r + 1];
            float a0 = 0.f, a1 = 0.f, a2 = 0.f, a3 = 0.f;
            for (int base = e0; base < e1; base += 64) {
                int cnt = e1 - base; if (cnt > 64) cnt = 64;
                int sidx = (lane < cnt) ? csr[base + lane] : 0;
                #pragma unroll 8
                for (int d = 0; d < cnt; d++) {
                    int s = __shfl(sidx, d);
                    ushort4 hv = reinterpret_cast<const ushort4*>(
                        (const unsigned short*)h + (size_t)s * FEATS)[lane];
                    a0 += bf2f(hv.x); a1 += bf2f(hv.y); a2 += bf2f(hv.z); a3 += bf2f(hv.w);
                }
            }
            float rc = 1.0f / fmaxf((float)(e1 - e0), 1.0f);
            ushort4 o;
            o.x = f2bf(a0 * rc); o.y = f2bf(a1 * rc); o.z = f2bf(a2 * rc); o.w = f2bf(a3 * rc);
            *reinterpret_cast<ushort4*>(&hmean[(size_t)r * FEATS + lane * 4]) = o;
        }
    }
}

// =====================================================================
// Lean GEMM (layers 0/1), r8-PROVEN single-buffer version: 64 rows x
// 128 cols per block, BK=64, global_load_lds width-16 into linear LDS
// with chunk^(row&7) swizzle. LDS 24KB -> 6 blocks/CU; implicit
// wave-level overlap does the pipelining (explicit dbuf regressed, r12).
// =====================================================================
__global__ __launch_bounds__(256) void k_gemm(
        const void* __restrict__ h, const unsigned short* __restrict__ hmean,
        const unsigned short* __restrict__ Wt, const void* __restrict__ bias,
        void* __restrict__ out, int M, const int* __restrict__ flag, int maybeF32) {
    const bool inF32 = (flag[1] == 0);
    const bool hF32 = maybeF32 && inF32;
    __shared__ __align__(16) unsigned short As[64 * 64];    // 8 KB
    __shared__ __align__(16) unsigned short Bs[128 * 64];   // 16 KB

    const int rb = (int)blockIdx.x >> 1;
    const int chalf = (int)blockIdx.x & 1;
    const int m0 = rb * 64;
    const int col0 = chalf * 128;
    const int tid = threadIdx.x;
    const int lane = tid & 63, w = tid >> 6;
    const int nh = lane & 15, q = lane >> 4;   // q in 0..3

    f32x4 acc[8];
    #pragma unroll
    for (int ci = 0; ci < 8; ci++) acc[ci] = (f32x4){0.f, 0.f, 0.f, 0.f};

    for (int kb = 0; kb < KTOT; kb += 64) {
        #pragma unroll
        for (int j = 0; j < 2; j++) {
            int t2 = tid + j * 256;
            int row = t2 >> 3, c = t2 & 7;
            int gr = m0 + row; if (gr > M - 1) gr = M - 1;
            int cs = c ^ (row & 7);            // pre-swizzled source chunk
            if (kb < 256) {
                if (hF32) {
                    const float* p = (const float*)h + (size_t)gr * FEATS + kb + cs * 8;
                    float4 a = *reinterpret_cast<const float4*>(p);
                    float4 b = *reinterpret_cast<const float4*>(p + 4);
                    unsigned short* d = &As[t2 * 8];
                    d[0]=f2bf(a.x); d[1]=f2bf(a.y); d[2]=f2bf(a.z); d[3]=f2bf(a.w);
                    d[4]=f2bf(b.x); d[5]=f2bf(b.y); d[6]=f2bf(b.z); d[7]=f2bf(b.w);
                } else {
                    ASYNC16((const unsigned short*)h + (size_t)gr * FEATS + kb + cs * 8,
                            &As[t2 * 8]);
                }
            } else {
                ASYNC16(hmean + (size_t)gr * FEATS + (kb - 256) + cs * 8, &As[t2 * 8]);
            }
        }
        #pragma unroll
        for (int j = 0; j < 4; j++) {
            int t2 = tid + j * 256;
            int n = t2 >> 3, c = t2 & 7;
            int cs = c ^ (n & 7);
            ASYNC16(Wt + (size_t)(col0 + n) * KTOT + kb + cs * 8, &Bs[t2 * 8]);
        }
        __syncthreads();

        #pragma unroll
        for (int s = 0; s < 2; s++) {
            const int arow = w * 16 + nh;
            const int qa = ((s * 4 + q) ^ (arow & 7));
            bf16x8 afr = *reinterpret_cast<const bf16x8*>(&As[arow * 64 + qa * 8]);
            #pragma unroll
            for (int ci = 0; ci < 8; ci++) {
                int n = ci * 16 + nh;
                int qb = ((s * 4 + q) ^ (n & 7));
                bf16x8 bfr = *reinterpret_cast<const bf16x8*>(&Bs[n * 64 + qb * 8]);
                acc[ci] = __builtin_amdgcn_mfma_f32_16x16x32_bf16(afr, bfr, acc[ci], 0, 0, 0);
            }
        }
        __syncthreads();
    }

    const int rbase = m0 + w * 16 + q * 4;
    const float sc = 1.0507009873554805f, al = 1.6732632423543772f;
    #pragma unroll
    for (int ci = 0; ci < 8; ci++) {
        int col = col0 + ci * 16 + nh;
        float b = inF32 ? ((const float*)bias)[col] : bf2f(((const unsigned short*)bias)[col]);
        #pragma unroll
        for (int rg = 0; rg < 4; rg++) {
            int r = rbase + rg;
            if (r < M) {
                float v = acc[ci][rg] + b;
                v = (v > 0.f) ? sc * v : sc * al * expm1f(v);
                ((unsigned short*)out)[(size_t)r * FEATS + col] = f2bf(v);
            }
        }
    }
}

// =====================================================================
// Layer-2 dual GEMM (single hX pass): S2 = hX @ Ws2 (f32, stride 64)
// AND P2 = hX @ Wn2 (bf16, stride 64). 64 rows x 128 cols, K=256.
// =====================================================================
__global__ __launch_bounds__(256) void k_gemm256d(
        const unsigned short* __restrict__ h, const unsigned short* __restrict__ Wt2s,
        const unsigned short* __restrict__ Wt2n, float* __restrict__ S2,
        unsigned short* __restrict__ P2, int M) {
    __shared__ __align__(16) unsigned short As[64 * SA];
    __shared__ __align__(16) unsigned short Bs[128 * SA];

    const int m0 = blockIdx.x * 64;
    const int tid = threadIdx.x;
    const int lane = tid & 63, w = tid >> 6;
    const int nh = lane & 15, q = lane >> 4;

    f32x4 acc[8];
    #pragma unroll
    for (int ci = 0; ci < 8; ci++) acc[ci] = (f32x4){0.f, 0.f, 0.f, 0.f};

    for (int kb = 0; kb < 256; kb += 32) {
        {
            int row = tid >> 2, seg = tid & 3;
            int gr = m0 + row; if (gr > M - 1) gr = M - 1;
            *reinterpret_cast<float4*>(&As[row * SA + seg * 8]) =
                *reinterpret_cast<const float4*>(h + (size_t)gr * FEATS + kb + seg * 8);
        }
        for (int u = tid; u < 128 * 4; u += 256) {
            int nn = u >> 2, seg = u & 3;
            const unsigned short* src = (nn < 64)
                ? Wt2s + (size_t)nn * 256 : Wt2n + (size_t)(nn - 64) * 256;
            *reinterpret_cast<float4*>(&Bs[nn * SA + seg * 8]) =
                *reinterpret_cast<const float4*>(src + kb + seg * 8);
        }
        __syncthreads();
        bf16x8 afr = *reinterpret_cast<const bf16x8*>(&As[(w * 16 + nh) * SA + q * 8]);
        #pragma unroll
        for (int ci = 0; ci < 8; ci++) {
            bf16x8 bfr = *reinterpret_cast<const bf16x8*>(&Bs[(ci * 16 + nh) * SA + q * 8]);
            acc[ci] = __builtin_amdgcn_mfma_f32_16x16x32_bf16(afr, bfr, acc[ci], 0, 0, 0);
        }
        __syncthreads();
    }

    const int rbase = m0 + w * 16 + q * 4;
    #pragma unroll
    for (int ci = 0; ci < 4; ci++) {       // self half -> S2 (f32)
        int col = ci * 16 + nh;
        #pragma unroll
        for (int rg = 0; rg < 4; rg++) {
            int r = rbase + rg;
            if (r < M) S2[(size_t)r * 64 + col] = acc[ci][rg];
        }
    }
    #pragma unroll
    for (int ci = 4; ci < 8; ci++) {       // neigh half -> P2 (bf16)
        int col = (ci - 4) * 16 + nh;
        #pragma unroll
        for (int rg = 0; rg < 4; rg++) {
            int r = rbase + rg;
            if (r < M) P2[(size_t)r * 64 + col] = f2bf(acc[ci][rg]);
        }
    }
}

// =====================================================================
// FUSED layer-2 tail: gather-mean of P2 (wave per row, 2 grp x 32 ln)
// + softmax(S2 + mean + b2) in-register. Full-exec shuffles (verified
// r11 fix): divergent ds_bpermute from inactive lanes returns 0.
// =====================================================================
__global__ __launch_bounds__(256) void k_aggrsm(
        const unsigned short* __restrict__ P, const float* __restrict__ S2,
        const int* __restrict__ off, const int* __restrict__ csr,
        const void* __restrict__ bias, void* __restrict__ out,
        int M, int C, const int* __restrict__ flag) {
    const bool inF32 = (flag[1] == 0);
    const int lane = threadIdx.x & 63;
    const int wid = (blockIdx.x * 256 + threadIdx.x) >> 6;
    const int nw = (gridDim.x * 256) >> 6;
    const int g = lane >> 5, li = lane & 31;
    for (int r = wid; r < M; r += nw) {
        const int e0 = off[r], e1 = off[r + 1];
        float a0 = 0.f, a1 = 0.f;
        #pragma unroll 4
        for (int base = e0; base < e1; base += 2) {
            int e = base + g;
            if (e < e1) {
                int s = csr[e];
                ushort2 hv = *reinterpret_cast<const ushort2*>(
                    P + (size_t)s * 64 + li * 2);
                a0 += bf2f(hv.x); a1 += bf2f(hv.y);
            }
        }
        a0 += __shfl_xor(a0, 32); a1 += __shfl_xor(a1, 32);   // all lanes hold totals
        float rc = 1.0f / fmaxf((float)(e1 - e0), 1.0f);
        // redistribute with FULL exec mask, then select
        float av0 = __shfl(a0, lane >> 1);
        float av1 = __shfl(a1, lane >> 1);
        float av = (lane & 1) ? av1 : av0;
        float v = -1e30f;
        if (lane < C) {
            float b = inF32 ? ((const float*)bias)[lane]
                            : bf2f(((const unsigned short*)bias)[lane]);
            v = S2[(size_t)r * 64 + lane] + av * rc + b;
        }
        float mx = v;
        #pragma unroll
        for (int mk = 1; mk <= 32; mk <<= 1) mx = fmaxf(mx, __shfl_xor(mx, mk));
        float e = (lane < C) ? __expf(v - mx) : 0.f;
        float s = e;
        #pragma unroll
        for (int mk = 1; mk <= 32; mk <<= 1) s += __shfl_xor(s, mk);
        float o = e / s;
        if (lane < C) {
            if (inF32) ((float*)out)[(size_t)r * C + lane] = o;
            else ((unsigned short*)out)[(size_t)r * C + lane] = f2bf(o);
        }
    }
}

// =====================================================================
// FALLBACK path kernels (workspace too small): original fused kernel +
// dual-dtype weight transpose. Verified-correct from earlier sessions.
// =====================================================================
template <bool F32>
__global__ void k_buildWt(const void* __restrict__ Ws, const void* __restrict__ Wn,
                          unsigned short* __restrict__ Wt, int N, int Npad,
                          const int* __restrict__ flag) {
    if (flag[1] != (F32 ? 0 : 1)) return;
    int idx = blockIdx.x * 256 + threadIdx.x;
    if (idx >= Npad * KTOT) return;
    int n = idx >> 9, k = idx & 511;
    unsigned short v = 0;
    if (n < N) {
        if (F32) {
            float fv = (k < 256) ? ((const float*)Ws)[k * N + n]
                                 : ((const float*)Wn)[(k - 256) * N + n];
            v = f2bf(fv);
        } else {
            v = (k < 256) ? ((const unsigned short*)Ws)[k * N + n]
                          : ((const unsigned short*)Wn)[(k - 256) * N + n];
        }
    }
    Wt[idx] = v;
}

template <bool F32>
__device__ __forceinline__ void stage8(const void* h, size_t elemOff, unsigned short* dst) {
    if (!F32) {
        *reinterpret_cast<float4*>(dst) =
            *reinterpret_cast<const float4*>((const unsigned short*)h + elemOff);
    } else {
        const float* p = (const float*)h + elemOff;
        float4 a = *reinterpret_cast<const float4*>(p);
        float4 b = *reinterpret_cast<const float4*>(p + 4);
        dst[0] = f2bf(a.x); dst[1] = f2bf(a.y); dst[2] = f2bf(a.z); dst[3] = f2bf(a.w);
        dst[4] = f2bf(b.x); dst[5] = f2bf(b.y); dst[6] = f2bf(b.z); dst[7] = f2bf(b.w);
    }
}

template <int NT, int ACT, bool HF32, bool BF32, bool OF32>
__global__ __launch_bounds__(256) void k_sage(
        const void* __restrict__ h, const int* __restrict__ off,
        const int* __restrict__ csr, const unsigned short* __restrict__ Wt,
        const void* __restrict__ bias, void* __restrict__ out,
        int M, int C, const int* __restrict__ flag, int want) {
    if (flag[1] != want) return;
    __shared__ __align__(16) unsigned short meanS[64 * MS];
    __shared__ __align__(16) unsigned short As[64 * SA];
    __shared__ __align__(16) unsigned short Bs[NT * 16 * SA];

    const int m0 = blockIdx.x * 64;
    const int tid = threadIdx.x;
    const int lane = tid & 63, w = tid >> 6;
    const int nh = lane & 15, q = lane >> 4;

    for (int i = 0; i < 16; i++) {
        int lr = w * 16 + i;
        int r = m0 + lr;
        int rr = (r < M) ? r : (M - 1);
        int e0 = off[rr], e1 = off[rr + 1];
        float a0 = 0.f, a1 = 0.f, a2 = 0.f, a3 = 0.f;
        #pragma unroll 8
        for (int j = e0; j < e1; j++) {
            int s = csr[j];
            if (HF32) {
                float4 hv = reinterpret_cast<const float4*>((const float*)h + (size_t)s * FEATS)[lane];
                a0 += hv.x; a1 += hv.y; a2 += hv.z; a3 += hv.w;
            } else {
                ushort4 hv = reinterpret_cast<const ushort4*>((const unsigned short*)h + (size_t)s * FEATS)[lane];
                a0 += bf2f(hv.x); a1 += bf2f(hv.y); a2 += bf2f(hv.z); a3 += bf2f(hv.w);
            }
        }
        float rc = 1.0f / fmaxf((float)(e1 - e0), 1.0f);
        ushort4 o;
        o.x = f2bf(a0 * rc); o.y = f2bf(a1 * rc); o.z = f2bf(a2 * rc); o.w = f2bf(a3 * rc);
        *reinterpret_cast<ushort4*>(&meanS[lr * MS + lane * 4]) = o;
    }
    __syncthreads();

    f32x4 acc[NT];
    #pragma unroll
    for (int ci = 0; ci < NT; ci++) acc[ci] = (f32x4){0.f, 0.f, 0.f, 0.f};

    for (int kb = 0; kb < KTOT; kb += 32) {
        const bool fromMean = (kb >= 256);
        if (!fromMean) {
            int row = tid >> 2, seg = tid & 3;
            int gr = m0 + row; if (gr > M - 1) gr = M - 1;
            stage8<HF32>(h, (size_t)gr * FEATS + kb + seg * 8, &As[row * SA + seg * 8]);
        }
        for (int u = tid; u < NT * 64; u += 256) {
            int nn = u >> 2, seg = u & 3;
            *reinterpret_cast<float4*>(&Bs[nn * SA + seg * 8]) =
                *reinterpret_cast<const float4*>(Wt + (size_t)nn * KTOT + kb + seg * 8);
        }
        __syncthreads();
        bf16x8 afr;
        if (!fromMean)
            afr = *reinterpret_cast<const bf16x8*>(&As[(w * 16 + nh) * SA + q * 8]);
        else
            afr = *reinterpret_cast<const bf16x8*>(&meanS[(w * 16 + nh) * MS + (kb - 256) + q * 8]);
        #pragma unroll
        for (int ci = 0; ci < NT; ci++) {
            bf16x8 bfr = *reinterpret_cast<const bf16x8*>(&Bs[(ci * 16 + nh) * SA + q * 8]);
            acc[ci] = __builtin_amdgcn_mfma_f32_16x16x32_bf16(afr, bfr, acc[ci], 0, 0, 0);
        }
        __syncthreads();
    }

    const int rbase = m0 + w * 16 + q * 4;
    if (ACT == 0) {
        const float sc = 1.0507009873554805f, al = 1.6732632423543772f;
        #pragma unroll
        for (int ci = 0; ci < NT; ci++) {
            int col = ci * 16 + nh;
            float b = BF32 ? ((const float*)bias)[col] : bf2f(((const unsigned short*)bias)[col]);
            #pragma unroll
            for (int rg = 0; rg < 4; rg++) {
                int r = rbase + rg;
                if (r < M) {
                    float v = acc[ci][rg] + b;
                    v = (v > 0.f) ? sc * v : sc * al * expm1f(v);
                    if (OF32) ((float*)out)[(size_t)r * (NT * 16) + col] = v;
                    else ((unsigned short*)out)[(size_t)r * (NT * 16) + col] = f2bf(v);
                }
            }
        }
    } else {
        #pragma unroll
        for (int rg = 0; rg < 4; rg++) {
            int r = rbase + rg;
            float vals[NT];
            float mx = -1e30f;
            #pragma unroll
            for (int ci = 0; ci < NT; ci++) {
                int col = ci * 16 + nh;
                float v = -1e30f;
                if (col < C) {
                    float b = BF32 ? ((const float*)bias)[col] : bf2f(((const unsigned short*)bias)[col]);
                    v = acc[ci][rg] + b;
                }
                vals[ci] = v;
                mx = fmaxf(mx, v);
            }
            #pragma unroll
            for (int mk = 1; mk <= 8; mk <<= 1) mx = fmaxf(mx, __shfl_xor(mx, mk));
            float s = 0.f;
            #pragma unroll
            for (int ci = 0; ci < NT; ci++) {
                float e = (vals[ci] <= -1e29f) ? 0.f : __expf(vals[ci] - mx);
                vals[ci] = e; s += e;
            }
            #pragma unroll
            for (int mk = 1; mk <= 8; mk <<= 1) s += __shfl_xor(s, mk);
            float inv = 1.f / s;
            if (r < M) {
                #pragma unroll
                for (int ci = 0; ci < NT; ci++) {
                    int col = ci * 16 + nh;
                    if (col < C) {
                        if (OF32) ((float*)out)[(size_t)r * C + col] = vals[ci] * inv;
                        else ((unsigned short*)out)[(size_t)r * C + col] = f2bf(vals[ci] * inv);
                    }
                }
            }
        }
    }
}

extern "C" void kernel_launch(void* const* d_in, const int* in_sizes, int n_in,
                              void* d_out, int out_size, void* d_ws, size_t ws_size,
                              hipStream_t stream) {
    const int* srcRaw = (const int*)d_in[1];
    const int* dstRaw = (const int*)d_in[2];
    const void* x   = d_in[0];
    const void* Ws0 = d_in[3]; const void* Wn0 = d_in[4]; const void* b0 = d_in[5];
    const void* Ws1 = d_in[6]; const void* Wn1 = d_in[7]; const void* b1 = d_in[8];
    const void* Ws2 = d_in[9]; const void* Wn2 = d_in[10]; const void* b2 = d_in[11];

    const int nNodes = in_sizes[0] / FEATS;   // 50000
    const int nE     = in_sizes[1];           // 800000
    const int C      = in_sizes[11];          // 47

    // ---- workspace carve ----
    char* ws = (char*)d_ws;
    size_t off_b = 0;
    auto carve = [&](size_t bytes) -> void* {
        void* p = (void*)(ws + off_b);
        off_b += (bytes + 255) & ~(size_t)255;
        return p;
    };
    int*            flag   = (int*)           carve(256);
    int*            deg    = (int*)           carve((size_t)nNodes * 4);
    int*            cursor = (int*)           carve((size_t)nNodes * 4);
    int*            off    = (int*)           carve((size_t)(nNodes + 1) * 4);
    int*            csr    = (int*)           carve((size_t)nE * 4);
    unsigned short* Wt0    = (unsigned short*)carve((size_t)256 * KTOT * 2);
    unsigned short* Wt1    = (unsigned short*)carve((size_t)256 * KTOT * 2);
    unsigned short* Wt2    = (unsigned short*)carve((size_t)64 * KTOT * 2);   // fallback combined
    unsigned short* Wt2s   = (unsigned short*)carve((size_t)64 * 256 * 2);
    unsigned short* Wt2n   = (unsigned short*)carve((size_t)64 * 256 * 2);
    int*            bsum   = (int*)           carve(4096);
    unsigned short* hA     = (unsigned short*)carve((size_t)nNodes * FEATS * 2);
    unsigned short* hmean  = (unsigned short*)carve((size_t)nNodes * FEATS * 2);
    const bool split = (off_b <= ws_size);
    // layer-2 buffers tile into hmean (dead for layer 2):
    //   S2 f32 (nN*64*4 B) | P2 bf16 (nN*64*2 B)
    const size_t l2n = (size_t)nNodes * 64;
    float*          S2 = (float*)hmean;                 // bytes [0, 4*l2n)
    unsigned short* P2 = hmean + l2n * 2;               // bytes [4*l2n, 6*l2n)
    // h2 lives in the (dead-after-layer-0, harness-restored) x input buffer
    unsigned short* hX = (unsigned short*)d_in[0];

    const int edgeBlocks = (nE + 255) / 256;
    const int nodeBlocks = (nNodes + 255) / 256;   // 196 <= 1024
    const int sageBlocks = (nNodes + 63) / 64;     // 782
    const int gemmBlocks = sageBlocks * 2;         // 64x128 tiles, col-half split
    const int aggrBlocks = 2048;

    // ---- prep: detect + CSR build + weight transposes (proven 8-dispatch) ----
    const unsigned short* xr = (const unsigned short*)x;
    k_detect<<<1, 256, 0, stream>>>(srcRaw, xr, nE, flag);
    hipError_t me = hipMemsetAsync(deg, 0, (size_t)nNodes * 4, stream);
    (void)me;
    k_count<<<edgeBlocks, 256, 0, stream>>>(dstRaw, deg, nE, nNodes, flag);
    k_bsum<<<nodeBlocks, 256, 0, stream>>>(deg, bsum, nNodes);
    k_scanb<<<1, 256, 0, stream>>>(bsum, nodeBlocks);
    k_offs<<<nodeBlocks, 256, 0, stream>>>(deg, bsum, off, cursor, nNodes);
    k_fill<<<edgeBlocks, 256, 0, stream>>>(srcRaw, dstRaw, cursor, csr, nE, nNodes, flag);

    if (split) {
        k_buildAll<<<(294912 + 255) / 256, 256, 0, stream>>>(
            Ws0, Wn0, Ws1, Wn1, Ws2, Wn2, Wt0, Wt1, Wt2s, Wt2n, C, flag);

        // ---- layer 0: x -> hA ----
        k_aggr<<<aggrBlocks, 256, 0, stream>>>(x, off, csr, hmean, nNodes, flag, 1);
        k_gemm<<<gemmBlocks, 256, 0, stream>>>(x, hmean, Wt0, b0, hA, nNodes, flag, 1);

        // ---- layer 1: hA -> hX (x buffer, x now dead) ----
        k_aggr<<<aggrBlocks, 256, 0, stream>>>(hA, off, csr, hmean, nNodes, flag, 0);
        k_gemm<<<gemmBlocks, 256, 0, stream>>>(hA, hmean, Wt1, b1, hX, nNodes, flag, 0);

        // ---- layer 2 (project-first, single hX pass):
        //      {S2 = hX@Ws2 (f32), P2 = hX@Wn2}; out = softmax(S2 + mean(P2[src]) + b2)
        k_gemm256d<<<sageBlocks, 256, 0, stream>>>(hX, Wt2s, Wt2n, S2, P2, nNodes);
        k_aggrsm<<<aggrBlocks, 256, 0, stream>>>(P2, S2, off, csr, b2, d_out,
                                                 nNodes, C, flag);
    } else {
        // ---- ws-too-small fallback: original fused path ----
        int wtB = (256 * KTOT + 255) / 256;
        k_buildWt<false><<<wtB, 256, 0, stream>>>(Ws0, Wn0, Wt0, 256, 256, flag);
        k_buildWt<true ><<<wtB, 256, 0, stream>>>(Ws0, Wn0, Wt0, 256, 256, flag);
        k_buildWt<false><<<wtB, 256, 0, stream>>>(Ws1, Wn1, Wt1, 256, 256, flag);
        k_buildWt<true ><<<wtB, 256, 0, stream>>>(Ws1, Wn1, Wt1, 256, 256, flag);
        int wtB2 = (64 * KTOT + 255) / 256;
        k_buildWt<false><<<wtB2, 256, 0, stream>>>(Ws2, Wn2, Wt2, C, 64, flag);
        k_buildWt<true ><<<wtB2, 256, 0, stream>>>(Ws2, Wn2, Wt2, C, 64, flag);
        k_sage<16, 0, false, false, false><<<sageBlocks, 256, 0, stream>>>(
            x, off, csr, Wt0, b0, hA, nNodes, 256, flag, 1);
        k_sage<16, 0, true, true, false><<<sageBlocks, 256, 0, stream>>>(
            x, off, csr, Wt0, b0, hA, nNodes, 256, flag, 0);
        k_sage<16, 0, false, false, false><<<sageBlocks, 256, 0, stream>>>(
            hA, off, csr, Wt1, b1, hX, nNodes, 256, flag, 1);
        k_sage<16, 0, false, true, false><<<sageBlocks, 256, 0, stream>>>(
            hA, off, csr, Wt1, b1, hX, nNodes, 256, flag, 0);
        k_sage<4, 1, false, false, false><<<sageBlocks, 256, 0, stream>>>(
            hX, off, csr, Wt2, b2, d_out, nNodes, C, flag, 1);
        k_sage<4, 1, false, true, true><<<sageBlocks, 256, 0, stream>>>(
            hX, off, csr, Wt2, b2, d_out, nNodes, C, flag, 0);
    }
}